// Round 6
// baseline (946.320 us; speedup 1.0000x reference)
//
#include <hip/hip_runtime.h>

#define NN 100000   // nodes
#define NE 1600000  // edges
#define IN_CH 41
#define EDIM 8
#define H 64
#define GNUM 256
#define ATOM 21
#define EPSV 1e-5f
#define EPW 16      // edges per wave in aggr (NE % EPW == 0)
#define MLPB 64     // threads per block in thread-per-node MLPs (1 wave)

#define NBLK_SCAN ((NN + 255) / 256)   // 391

typedef unsigned short u16;
typedef unsigned int u32;
typedef unsigned long long u64;

__device__ __forceinline__ u16 f2bf(float f) {
    u32 u = __float_as_uint(f);
    u32 r = (u + 0x7FFFu + ((u >> 16) & 1u)) >> 16;   // RNE
    return (u16)r;
}
__device__ __forceinline__ float bf2f(u16 u) {
    return __uint_as_float(((u32)u) << 16);
}

// ---- partition: mask per node, ballot-compact ids into lig/prot lists ------
__global__ __launch_bounds__(256) void partition_kernel(
    const float* __restrict__ x, int* __restrict__ ctr,   // ctr[0]=lig, ctr[1]=prot
    int* __restrict__ lig_list, int* __restrict__ prot_list)
{
    const int n = blockIdx.x * 256 + threadIdx.x;
    const int lane = threadIdx.x & 63;
    float m = 0.0f;
    if (n < NN) {
        const float* xr = x + (size_t)n * IN_CH + ATOM;
#pragma unroll
        for (int d = 0; d < IN_CH - ATOM; ++d) m += fabsf(xr[d]);
    }
    const bool valid = n < NN;
    const bool prot = valid && (m > 1e-6f);
    const bool lig = valid && !prot;

    const u64 bl = __ballot(lig);
    const u64 bp = __ballot(prot);
    const u64 below = (lane == 63) ? ~0ull >> 1 : ((1ull << lane) - 1);
    int base_l = 0, base_p = 0;
    if (lane == 0) {
        if (bl) base_l = atomicAdd(&ctr[0], (int)__popcll(bl));
        if (bp) base_p = atomicAdd(&ctr[1], (int)__popcll(bp));
    }
    base_l = __shfl(base_l, 0, 64);
    base_p = __shfl(base_p, 0, 64);
    if (lig)  lig_list [base_l + __popcll(bl & below)] = n;
    if (prot) prot_list[base_p + __popcll(bp & below)] = n;
}

// ---- encoder MLP: thread-per-node over a list, wave-uniform weights --------
__global__ __launch_bounds__(MLPB) void enc_mlp_kernel(
    const int* __restrict__ list, const int* __restrict__ count,
    const float* __restrict__ x,
    const float* __restrict__ W1, const float* __restrict__ b1,
    const float* __restrict__ W2, const float* __restrict__ b2,
    float* __restrict__ h, u16* __restrict__ h16)
{
    __shared__ float ts[MLPB * 65];
    const int t = threadIdx.x;
    const int i = blockIdx.x * MLPB + t;
    if (i >= *count) return;
    const int n = list[i];
    const float* xrow = x + (size_t)n * IN_CH;

    float acc[H];
#pragma unroll
    for (int d = 0; d < H; ++d) acc[d] = b1[d];
    for (int k = 0; k < IN_CH; ++k) {
        const float xv = xrow[k];
        const float* w = W1 + (size_t)k * H;
#pragma unroll
        for (int d = 0; d < H; ++d) acc[d] = fmaf(xv, w[d], acc[d]);
    }
#pragma unroll
    for (int d = 0; d < H; ++d) ts[t * 65 + d] = fmaxf(acc[d], 0.0f);

#pragma unroll
    for (int d = 0; d < H; ++d) acc[d] = b2[d];
    for (int k4 = 0; k4 < H / 4; ++k4) {
        const float* w = W2 + (size_t)k4 * 4 * H;
        const float z0 = ts[t * 65 + k4 * 4 + 0];
        const float z1 = ts[t * 65 + k4 * 4 + 1];
        const float z2 = ts[t * 65 + k4 * 4 + 2];
        const float z3 = ts[t * 65 + k4 * 4 + 3];
#pragma unroll
        for (int d = 0; d < H; ++d) acc[d] = fmaf(z0, w[d], acc[d]);
#pragma unroll
        for (int d = 0; d < H; ++d) acc[d] = fmaf(z1, w[H + d], acc[d]);
#pragma unroll
        for (int d = 0; d < H; ++d) acc[d] = fmaf(z2, w[2 * H + d], acc[d]);
#pragma unroll
        for (int d = 0; d < H; ++d) acc[d] = fmaf(z3, w[3 * H + d], acc[d]);
    }
    float* hrow = h + (size_t)n * H;
    u32* h16row = (u32*)(h16 + (size_t)n * H);
#pragma unroll
    for (int d4 = 0; d4 < H / 4; ++d4) {
        float v0 = fmaxf(acc[4 * d4 + 0], 0.0f);
        float v1 = fmaxf(acc[4 * d4 + 1], 0.0f);
        float v2 = fmaxf(acc[4 * d4 + 2], 0.0f);
        float v3 = fmaxf(acc[4 * d4 + 3], 0.0f);
        ((float4*)hrow)[d4] = make_float4(v0, v1, v2, v3);
        h16row[2 * d4 + 0] = (u32)f2bf(v0) | ((u32)f2bf(v1) << 16);
        h16row[2 * d4 + 1] = (u32)f2bf(v2) | ((u32)f2bf(v3) << 16);
    }
}

// ---------------- per-graph node ranges (batch is sorted) -------------------
__global__ void bounds_kernel(const int* __restrict__ batch, int* __restrict__ start)
{
    int g = blockIdx.x * blockDim.x + threadIdx.x;
    if (g > GNUM) return;
    int lo = 0, hi = NN;
    while (lo < hi) {
        int mid = (lo + hi) >> 1;
        if (batch[mid] < g) lo = mid + 1; else hi = mid;
    }
    start[g] = lo;
}

// ---------------- CSR build ------------------------------------------------
__global__ __launch_bounds__(256) void hist_kernel(
    const int* __restrict__ ei, int* __restrict__ deg)
{
    int e = blockIdx.x * blockDim.x + threadIdx.x;
    if (e < NE) atomicAdd(&deg[ei[NE + e]], 1);
}

__global__ __launch_bounds__(256) void scan_a_kernel(
    const int* __restrict__ deg, int* __restrict__ row_start, int* __restrict__ bsum)
{
    __shared__ int s[256];
    const int t = threadIdx.x;
    const int idx = blockIdx.x * 256 + t;
    int v = (idx < NN) ? deg[idx] : 0;
    s[t] = v;
    __syncthreads();
#pragma unroll
    for (int off = 1; off < 256; off <<= 1) {
        int tmp = (t >= off) ? s[t - off] : 0;
        __syncthreads();
        s[t] += tmp;
        __syncthreads();
    }
    if (idx < NN) row_start[idx] = s[t] - v;  // exclusive
    if (t == 255) bsum[blockIdx.x] = s[255];
}

__global__ __launch_bounds__(512) void scan_b_kernel(int* __restrict__ bsum)
{
    __shared__ int s[512];
    const int t = threadIdx.x;
    int v = (t < NBLK_SCAN) ? bsum[t] : 0;
    s[t] = v;
    __syncthreads();
#pragma unroll
    for (int off = 1; off < 512; off <<= 1) {
        int tmp = (t >= off) ? s[t - off] : 0;
        __syncthreads();
        s[t] += tmp;
        __syncthreads();
    }
    if (t < NBLK_SCAN) bsum[t] = s[t] - v;  // exclusive
}

__global__ __launch_bounds__(256) void scan_c_kernel(
    int* __restrict__ row_start, const int* __restrict__ bsum, int* __restrict__ cursor)
{
    const int idx = blockIdx.x * 256 + threadIdx.x;
    if (idx < NN) {
        int rs = row_start[idx] + bsum[blockIdx.x];
        row_start[idx] = rs;
        cursor[idx] = rs;
    } else if (idx == NN) {
        row_start[NN] = NE;
    }
}

// fill: perm2[pos] = (src,dst) ; eab[pos] = bf16x8(edge_attr[e])
__global__ __launch_bounds__(256) void fill_kernel(
    const int* __restrict__ ei, const float* __restrict__ ea,
    int* __restrict__ cursor,
    int2* __restrict__ perm2, uint4* __restrict__ eab)
{
    int e = blockIdx.x * blockDim.x + threadIdx.x;
    if (e >= NE) return;
    int src = ei[e];
    int dst = ei[NE + e];
    int pos = atomicAdd(&cursor[dst], 1);
    perm2[pos] = make_int2(src, dst);
    const float4* e4 = (const float4*)(ea + (size_t)e * EDIM);
    float4 a = e4[0], b = e4[1];
    uint4 u;
    u.x = (u32)f2bf(a.x) | ((u32)f2bf(a.y) << 16);
    u.y = (u32)f2bf(a.z) | ((u32)f2bf(a.w) << 16);
    u.z = (u32)f2bf(b.x) | ((u32)f2bf(b.y) << 16);
    u.w = (u32)f2bf(b.z) | ((u32)f2bf(b.w) << 16);
    eab[pos] = u;
}

// ---- edge-centric aggregation: one wave per 16 consecutive CSR edges -------
__global__ __launch_bounds__(256) void aggr_kernel(
    const int2* __restrict__ perm2,
    const u32* __restrict__ eab32,
    const float* __restrict__ We, const float* __restrict__ be,
    const u16* __restrict__ h16, float* __restrict__ h)
{
    const int lane = threadIdx.x & 63;
    const int chunk = blockIdx.x * 4 + (threadIdx.x >> 6);
    const int base = chunk * EPW;

    float we_r[EDIM];
#pragma unroll
    for (int d = 0; d < EDIM; ++d) we_r[d] = We[d * H + lane];
    const float be_r = be[lane];

    const int2 pd = perm2[base + (lane & 15)];
    const u32 eu = eab32[(size_t)base * 4 + lane];

    float hv[EPW];
#pragma unroll
    for (int j = 0; j < EPW; ++j) {
        const int sj = __builtin_amdgcn_readlane(pd.x, j);
        hv[j] = bf2f(h16[(size_t)sj * H + lane]);
    }

    float acc = 0.0f;
    int cur = __builtin_amdgcn_readlane(pd.y, 0);
#pragma unroll
    for (int j = 0; j < EPW; ++j) {
        const int dj = __builtin_amdgcn_readlane(pd.y, j);
        float msg = be_r;
#pragma unroll
        for (int p = 0; p < 4; ++p) {
            const u32 w2 = __builtin_amdgcn_readlane(eu, j * 4 + p);
            msg = fmaf(__uint_as_float(w2 << 16), we_r[2 * p], msg);
            msg = fmaf(__uint_as_float(w2 & 0xffff0000u), we_r[2 * p + 1], msg);
        }
        if (dj != cur) {                       // wave-uniform branch
            unsafeAtomicAdd(&h[(size_t)cur * H + lane], acc);
            acc = 0.0f;
            cur = dj;
        }
        acc += fmaxf(hv[j] + msg, 0.0f);
    }
    unsafeAtomicAdd(&h[(size_t)cur * H + lane], acc);
}

// ---------------- node MLP (in place): thread-per-node, scalar weights ------
__global__ __launch_bounds__(MLPB) void node_mlp_kernel(
    const float* __restrict__ W1, const float* __restrict__ b1,
    const float* __restrict__ W2, const float* __restrict__ b2,
    float* __restrict__ h)
{
    __shared__ float ts[MLPB * 65];
    const int t = threadIdx.x;
    const int n = blockIdx.x * MLPB + t;
    if (n >= NN) return;
    float* hrow = h + (size_t)n * H;

    float acc[H];
#pragma unroll
    for (int d = 0; d < H; ++d) acc[d] = b1[d];
    for (int k4 = 0; k4 < H / 4; ++k4) {
        const float4 zc = ((const float4*)hrow)[k4];
        const float* w = W1 + (size_t)k4 * 4 * H;
#pragma unroll
        for (int d = 0; d < H; ++d) acc[d] = fmaf(zc.x, w[d], acc[d]);
#pragma unroll
        for (int d = 0; d < H; ++d) acc[d] = fmaf(zc.y, w[H + d], acc[d]);
#pragma unroll
        for (int d = 0; d < H; ++d) acc[d] = fmaf(zc.z, w[2 * H + d], acc[d]);
#pragma unroll
        for (int d = 0; d < H; ++d) acc[d] = fmaf(zc.w, w[3 * H + d], acc[d]);
    }
#pragma unroll
    for (int d = 0; d < H; ++d) ts[t * 65 + d] = fmaxf(acc[d], 0.0f);

#pragma unroll
    for (int d = 0; d < H; ++d) acc[d] = b2[d];
    for (int k4 = 0; k4 < H / 4; ++k4) {
        const float* w = W2 + (size_t)k4 * 4 * H;
        const float z0 = ts[t * 65 + k4 * 4 + 0];
        const float z1 = ts[t * 65 + k4 * 4 + 1];
        const float z2 = ts[t * 65 + k4 * 4 + 2];
        const float z3 = ts[t * 65 + k4 * 4 + 3];
#pragma unroll
        for (int d = 0; d < H; ++d) acc[d] = fmaf(z0, w[d], acc[d]);
#pragma unroll
        for (int d = 0; d < H; ++d) acc[d] = fmaf(z1, w[H + d], acc[d]);
#pragma unroll
        for (int d = 0; d < H; ++d) acc[d] = fmaf(z2, w[2 * H + d], acc[d]);
#pragma unroll
        for (int d = 0; d < H; ++d) acc[d] = fmaf(z3, w[3 * H + d], acc[d]);
    }
#pragma unroll
    for (int d4 = 0; d4 < H / 4; ++d4)
        ((float4*)hrow)[d4] = make_float4(acc[4 * d4], acc[4 * d4 + 1],
                                          acc[4 * d4 + 2], acc[4 * d4 + 3]);
}

// ------- GraphNorm + relu, in place; also refresh bf16 mirror ---------------
__global__ __launch_bounds__(256) void graphnorm_kernel(
    float* __restrict__ h, u16* __restrict__ h16,
    const int* __restrict__ start,
    const float* __restrict__ w, const float* __restrict__ b,
    const float* __restrict__ a)
{
    __shared__ float red1[4][H], red2[4][H];
    __shared__ float amean_s[H], rstd_s[H];
    const int g = blockIdx.x;
    const int lane = threadIdx.x & 63;
    const int wv = threadIdx.x >> 6;
    const int s = start[g], e = start[g + 1];

    float s1 = 0.f, s2 = 0.f;
    for (int i = s + wv; i < e; i += 4) {
        float v = h[(size_t)i * H + lane];
        s1 += v; s2 += v * v;
    }
    red1[wv][lane] = s1; red2[wv][lane] = s2;
    __syncthreads();
    if (threadIdx.x < H) {
        float t1 = red1[0][lane] + red1[1][lane] + red1[2][lane] + red1[3][lane];
        float t2 = red2[0][lane] + red2[1][lane] + red2[2][lane] + red2[3][lane];
        float cnt = fmaxf((float)(e - s), 1.0f);
        float mean = t1 / cnt;
        float alpha = a[lane];
        float var = t2 / cnt - (2.0f * alpha - alpha * alpha) * mean * mean;
        var = fmaxf(var, 0.0f);
        amean_s[lane] = alpha * mean;
        rstd_s[lane] = rsqrtf(var + EPSV);
    }
    __syncthreads();
    const float am = amean_s[lane], rstd = rstd_s[lane];
    const float ww = w[lane], bb = b[lane];
    for (int i = s + wv; i < e; i += 4) {
        float v = (h[(size_t)i * H + lane] - am) * rstd * ww + bb;
        v = fmaxf(v, 0.0f);
        h[(size_t)i * H + lane] = v;
        h16[(size_t)i * H + lane] = f2bf(v);
    }
}

// ---------------- pool + readout: out[g] ------------------------------------
__global__ __launch_bounds__(256) void final_kernel(
    const float* __restrict__ h, const int* __restrict__ start,
    const float* __restrict__ W1, const float* __restrict__ b1,
    const float* __restrict__ W2, const float* __restrict__ b2,
    float* __restrict__ out)
{
    __shared__ float red[4][H];
    __shared__ float g_s[H];
    const int g = blockIdx.x;
    const int lane = threadIdx.x & 63;
    const int wv = threadIdx.x >> 6;
    const int s = start[g], e = start[g + 1];

    float s1 = 0.f;
    for (int i = s + wv; i < e; i += 4) s1 += h[(size_t)i * H + lane];
    red[wv][lane] = s1;
    __syncthreads();
    if (threadIdx.x < H)
        g_s[lane] = red[0][lane] + red[1][lane] + red[2][lane] + red[3][lane];
    __syncthreads();
    if (threadIdx.x < H) {
        float acc = b1[lane];
#pragma unroll
        for (int d = 0; d < H; ++d)
            acc = fmaf(g_s[d], W1[d * H + lane], acc);
        float r = fmaxf(acc, 0.0f);
        float v = r * W2[lane];
#pragma unroll
        for (int o = 32; o > 0; o >>= 1) v += __shfl_xor(v, o, 64);
        if (lane == 0) out[g] = v + b2[0];
    }
}

extern "C" void kernel_launch(void* const* d_in, const int* in_sizes, int n_in,
                              void* d_out, int out_size, void* d_ws, size_t ws_size,
                              hipStream_t stream)
{
    const float* x      = (const float*)d_in[0];
    const int*   ei     = (const int*)  d_in[1];
    const float* ea     = (const float*)d_in[2];
    const int*   batch  = (const int*)  d_in[3];
    const float* ligW1  = (const float*)d_in[4];
    const float* ligb1  = (const float*)d_in[5];
    const float* ligW2  = (const float*)d_in[6];
    const float* ligb2  = (const float*)d_in[7];
    const float* protW1 = (const float*)d_in[8];
    const float* protb1 = (const float*)d_in[9];
    const float* protW2 = (const float*)d_in[10];
    const float* protb2 = (const float*)d_in[11];
    const float* convWe = (const float*)d_in[12];
    const float* convbe = (const float*)d_in[13];
    const float* convW1 = (const float*)d_in[14];
    const float* convb1 = (const float*)d_in[15];
    const float* convW2 = (const float*)d_in[16];
    const float* convb2 = (const float*)d_in[17];
    const float* normw  = (const float*)d_in[18];
    const float* normb  = (const float*)d_in[19];
    const float* norma  = (const float*)d_in[20];
    const float* outW1  = (const float*)d_in[21];
    const float* outb1  = (const float*)d_in[22];
    const float* outW2  = (const float*)d_in[23];
    const float* outb2  = (const float*)d_in[24];

    float* out = (float*)d_out;

    // workspace layout (16B-aligned blocks first)
    float* h         = (float*)d_ws;                    // NN*H f32      25.6 MB
    uint4* eab       = (uint4*)(h + (size_t)NN * H);    // NE uint4      25.6 MB
    int2*  perm2     = (int2*)(eab + (size_t)NE);       // NE int2       12.8 MB
    u16*   h16       = (u16*)(perm2 + (size_t)NE);      // NN*H u16      12.8 MB
    int*   row_start = (int*)(h16 + (size_t)NN * H);    // NN+1
    int*   cursor    = row_start + (NN + 1);            // NN
    int*   deg       = cursor + NN;                     // NN   (zeroed)
    int*   ctr       = deg + NN;                        // 2    (zeroed, same memset)
    int*   bsum      = ctr + 2;                         // 512
    int*   start     = bsum + 512;                      // GNUM+1
    int*   lig_list  = start + (GNUM + 1);              // NN
    int*   prot_list = lig_list + NN;                   // NN

    // zero deg + ctr in one shot
    hipMemsetAsync(deg, 0, ((size_t)NN + 2) * sizeof(int), stream);

    partition_kernel<<<(NN + 255) / 256, 256, 0, stream>>>(x, ctr, lig_list, prot_list);
    const int mlp_blocks = (NN + MLPB - 1) / MLPB;
    enc_mlp_kernel<<<mlp_blocks, MLPB, 0, stream>>>(
        lig_list, &ctr[0], x, ligW1, ligb1, ligW2, ligb2, h, h16);
    enc_mlp_kernel<<<mlp_blocks, MLPB, 0, stream>>>(
        prot_list, &ctr[1], x, protW1, protb1, protW2, protb2, h, h16);

    bounds_kernel<<<2, 256, 0, stream>>>(batch, start);

    // ---- CSR build (once per launch) ----
    hist_kernel<<<(NE + 255) / 256, 256, 0, stream>>>(ei, deg);
    scan_a_kernel<<<NBLK_SCAN, 256, 0, stream>>>(deg, row_start, bsum);
    scan_b_kernel<<<1, 512, 0, stream>>>(bsum);
    scan_c_kernel<<<NBLK_SCAN, 256, 0, stream>>>(row_start, bsum, cursor);
    fill_kernel<<<(NE + 255) / 256, 256, 0, stream>>>(ei, ea, cursor, perm2, eab);

    const int aggr_blocks = NE / EPW / 4;   // 25000, exact
    for (int l = 0; l < 3; ++l) {
        aggr_kernel<<<aggr_blocks, 256, 0, stream>>>(
            perm2, (const u32*)eab,
            convWe + (size_t)l * EDIM * H, convbe + (size_t)l * H, h16, h);
        node_mlp_kernel<<<mlp_blocks, MLPB, 0, stream>>>(
            convW1 + (size_t)l * H * H, convb1 + (size_t)l * H,
            convW2 + (size_t)l * H * H, convb2 + (size_t)l * H, h);
        graphnorm_kernel<<<GNUM, 256, 0, stream>>>(
            h, h16, start, normw + (size_t)l * H, normb + (size_t)l * H, norma + (size_t)l * H);
    }
    final_kernel<<<GNUM, 256, 0, stream>>>(h, start, outW1, outb1, outW2, outb2, out);
}

// Round 7
// 938.382 us; speedup vs baseline: 1.0085x; 1.0085x over previous
//
#include <hip/hip_runtime.h>

#define NN 100000   // nodes
#define NE 1600000  // edges
#define IN_CH 41
#define EDIM 8
#define H 64
#define GNUM 256
#define ATOM 21
#define EPSV 1e-5f
#define EPW 16      // edges per wave in aggr (NE % EPW == 0)
#define MLPB 64     // threads per block in thread-per-node MLPs (1 wave)

#define NB 128      // dst buckets (dst>>10 -> 0..97)
#define VPT 8       // edges per thread in bucket kernels
#define EPB (256 * VPT)                    // 2048 edges per block
#define NBLK_E ((NE + EPB - 1) / EPB)      // 782
#define NBLK_SCAN ((NN + 255) / 256)       // 391

typedef unsigned short u16;
typedef unsigned int u32;
typedef unsigned long long u64;

__device__ __forceinline__ u16 f2bf(float f) {
    u32 u = __float_as_uint(f);
    u32 r = (u + 0x7FFFu + ((u >> 16) & 1u)) >> 16;   // RNE
    return (u16)r;
}
__device__ __forceinline__ float bf2f(u16 u) {
    return __uint_as_float(((u32)u) << 16);
}

// ---- partition: mask per node -> one compacted list (lig front, prot back) -
__global__ __launch_bounds__(256) void partition_kernel(
    const float* __restrict__ x, int* __restrict__ ctr,   // ctr[0]=lig, ctr[1]=prot
    int* __restrict__ nlist)
{
    const int n = blockIdx.x * 256 + threadIdx.x;
    const int lane = threadIdx.x & 63;
    float m = 0.0f;
    if (n < NN) {
        const float* xr = x + (size_t)n * IN_CH + ATOM;
#pragma unroll
        for (int d = 0; d < IN_CH - ATOM; ++d) m += fabsf(xr[d]);
    }
    const bool valid = n < NN;
    const bool prot = valid && (m > 1e-6f);
    const bool lig = valid && !prot;

    const u64 bl = __ballot(lig);
    const u64 bp = __ballot(prot);
    const u64 below = (1ull << (lane & 63)) - 1ull;  // lane 63 handled below
    const u64 below_m = (lane == 63) ? (~0ull >> 1) : below;
    int base_l = 0, base_p = 0;
    if (lane == 0) {
        if (bl) base_l = atomicAdd(&ctr[0], (int)__popcll(bl));
        if (bp) base_p = atomicAdd(&ctr[1], (int)__popcll(bp));
    }
    base_l = __shfl(base_l, 0, 64);
    base_p = __shfl(base_p, 0, 64);
    if (lig)  nlist[base_l + (int)__popcll(bl & below_m)] = n;
    if (prot) nlist[NN - 1 - (base_p + (int)__popcll(bp & below_m))] = n | 0x80000000;
}

// ---- encoder MLP body: thread-per-node, wave-uniform weights ---------------
__device__ __forceinline__ void enc_body(
    int n, const float* __restrict__ x,
    const float* __restrict__ W1, const float* __restrict__ b1,
    const float* __restrict__ W2, const float* __restrict__ b2,
    float* __restrict__ h, u16* __restrict__ h16, float* __restrict__ ts)
{
    const float* xrow = x + (size_t)n * IN_CH;
    float acc[H];
#pragma unroll
    for (int d = 0; d < H; ++d) acc[d] = b1[d];
    for (int k = 0; k < IN_CH; ++k) {
        const float xv = xrow[k];
        const float* w = W1 + (size_t)k * H;
#pragma unroll
        for (int d = 0; d < H; ++d) acc[d] = fmaf(xv, w[d], acc[d]);
    }
#pragma unroll
    for (int d = 0; d < H; ++d) ts[d] = fmaxf(acc[d], 0.0f);

#pragma unroll
    for (int d = 0; d < H; ++d) acc[d] = b2[d];
    for (int k4 = 0; k4 < H / 4; ++k4) {
        const float* w = W2 + (size_t)k4 * 4 * H;
        const float z0 = ts[k4 * 4 + 0];
        const float z1 = ts[k4 * 4 + 1];
        const float z2 = ts[k4 * 4 + 2];
        const float z3 = ts[k4 * 4 + 3];
#pragma unroll
        for (int d = 0; d < H; ++d) acc[d] = fmaf(z0, w[d], acc[d]);
#pragma unroll
        for (int d = 0; d < H; ++d) acc[d] = fmaf(z1, w[H + d], acc[d]);
#pragma unroll
        for (int d = 0; d < H; ++d) acc[d] = fmaf(z2, w[2 * H + d], acc[d]);
#pragma unroll
        for (int d = 0; d < H; ++d) acc[d] = fmaf(z3, w[3 * H + d], acc[d]);
    }
    float* hrow = h + (size_t)n * H;
    u32* h16row = (u32*)(h16 + (size_t)n * H);
#pragma unroll
    for (int d4 = 0; d4 < H / 4; ++d4) {
        float v0 = fmaxf(acc[4 * d4 + 0], 0.0f);
        float v1 = fmaxf(acc[4 * d4 + 1], 0.0f);
        float v2 = fmaxf(acc[4 * d4 + 2], 0.0f);
        float v3 = fmaxf(acc[4 * d4 + 3], 0.0f);
        ((float4*)hrow)[d4] = make_float4(v0, v1, v2, v3);
        h16row[2 * d4 + 0] = (u32)f2bf(v0) | ((u32)f2bf(v1) << 16);
        h16row[2 * d4 + 1] = (u32)f2bf(v2) | ((u32)f2bf(v3) << 16);
    }
}

// one dispatch; waves are type-uniform except the single lig/prot boundary
__global__ __launch_bounds__(MLPB) void enc_kernel(
    const int* __restrict__ nlist, const float* __restrict__ x,
    const float* __restrict__ lW1, const float* __restrict__ lb1,
    const float* __restrict__ lW2, const float* __restrict__ lb2,
    const float* __restrict__ pW1, const float* __restrict__ pb1,
    const float* __restrict__ pW2, const float* __restrict__ pb2,
    float* __restrict__ h, u16* __restrict__ h16)
{
    __shared__ float ts[MLPB * 65];
    const int t = threadIdx.x;
    const int i = blockIdx.x * MLPB + t;
    if (i >= NN) return;
    const int raw = nlist[i];
    const bool prot = raw < 0;
    const int n = raw & 0x7fffffff;
    float* myts = &ts[t * 65];
    if (__any(!prot)) {
        if (!prot) enc_body(n, x, lW1, lb1, lW2, lb2, h, h16, myts);
    }
    if (__any(prot)) {
        if (prot) enc_body(n, x, pW1, pb1, pW2, pb2, h, h16, myts);
    }
}

// ---------------- per-graph node ranges (batch is sorted) -------------------
__global__ void bounds_kernel(const int* __restrict__ batch, int* __restrict__ start)
{
    int g = blockIdx.x * blockDim.x + threadIdx.x;
    if (g > GNUM) return;
    int lo = 0, hi = NN;
    while (lo < hi) {
        int mid = (lo + hi) >> 1;
        if (batch[mid] < g) lo = mid + 1; else hi = mid;
    }
    start[g] = lo;
}

// ---- bucket+degree histogram: deg[dst]++ (global) + bucket counts ----------
__global__ __launch_bounds__(256) void bhist_kernel(
    const int* __restrict__ ei, int* __restrict__ deg, int* __restrict__ gbcount)
{
    __shared__ int cnt[NB];
    const int t = threadIdx.x;
    if (t < NB) cnt[t] = 0;
    __syncthreads();
    const int base = blockIdx.x * EPB;
#pragma unroll
    for (int v = 0; v < VPT; ++v) {
        const int e = base + v * 256 + t;
        if (e < NE) {
            const int d = ei[NE + e];
            atomicAdd(&deg[d], 1);
            atomicAdd(&cnt[d >> 10], 1);
        }
    }
    __syncthreads();
    if (t < NB && cnt[t]) atomicAdd(&gbcount[t], cnt[t]);
}

// ---- exclusive scan of the 128 bucket counts -> gcur -----------------------
__global__ __launch_bounds__(NB) void bscan_kernel(
    const int* __restrict__ gbcount, int* __restrict__ gcur)
{
    __shared__ int s[NB];
    const int t = threadIdx.x;
    const int v = gbcount[t];
    s[t] = v;
    __syncthreads();
#pragma unroll
    for (int off = 1; off < NB; off <<= 1) {
        int tmp = (t >= off) ? s[t - off] : 0;
        __syncthreads();
        s[t] += tmp;
        __syncthreads();
    }
    gcur[t] = s[t] - v;
}

// ---------------- node-degree scans (row_start, cursor) ---------------------
__global__ __launch_bounds__(256) void scan_a_kernel(
    const int* __restrict__ deg, int* __restrict__ row_start, int* __restrict__ bsum)
{
    __shared__ int s[256];
    const int t = threadIdx.x;
    const int idx = blockIdx.x * 256 + t;
    int v = (idx < NN) ? deg[idx] : 0;
    s[t] = v;
    __syncthreads();
#pragma unroll
    for (int off = 1; off < 256; off <<= 1) {
        int tmp = (t >= off) ? s[t - off] : 0;
        __syncthreads();
        s[t] += tmp;
        __syncthreads();
    }
    if (idx < NN) row_start[idx] = s[t] - v;  // exclusive
    if (t == 255) bsum[blockIdx.x] = s[255];
}

__global__ __launch_bounds__(512) void scan_b_kernel(int* __restrict__ bsum)
{
    __shared__ int s[512];
    const int t = threadIdx.x;
    int v = (t < NBLK_SCAN) ? bsum[t] : 0;
    s[t] = v;
    __syncthreads();
#pragma unroll
    for (int off = 1; off < 512; off <<= 1) {
        int tmp = (t >= off) ? s[t - off] : 0;
        __syncthreads();
        s[t] += tmp;
        __syncthreads();
    }
    if (t < NBLK_SCAN) bsum[t] = s[t] - v;  // exclusive
}

__global__ __launch_bounds__(256) void scan_c_kernel(
    int* __restrict__ row_start, const int* __restrict__ bsum, int* __restrict__ cursor)
{
    const int idx = blockIdx.x * 256 + threadIdx.x;
    if (idx < NN) {
        int rs = row_start[idx] + bsum[blockIdx.x];
        row_start[idx] = rs;
        cursor[idx] = rs;
    } else if (idx == NN) {
        row_start[NN] = NE;
    }
}

// ---- phase 1: LDS-ranked bucket partition, coalesced run writes ------------
__global__ __launch_bounds__(256) void p1_kernel(
    const int* __restrict__ ei, const float* __restrict__ ea,
    int* __restrict__ gcur,
    int2* __restrict__ tmp_sd, uint4* __restrict__ tmp_eab)
{
    __shared__ int cnt[NB];
    __shared__ int cur[NB];
    const int t = threadIdx.x;
    if (t < NB) cnt[t] = 0;
    __syncthreads();
    const int base = blockIdx.x * EPB;
    int dstv[VPT];
#pragma unroll
    for (int v = 0; v < VPT; ++v) {
        const int e = base + v * 256 + t;
        dstv[v] = -1;
        if (e < NE) {
            dstv[v] = ei[NE + e];
            atomicAdd(&cnt[dstv[v] >> 10], 1);
        }
    }
    __syncthreads();
    if (t < NB) cur[t] = cnt[t] ? atomicAdd(&gcur[t], cnt[t]) : 0;
    __syncthreads();
#pragma unroll
    for (int v = 0; v < VPT; ++v) {
        const int e = base + v * 256 + t;
        if (e < NE) {
            const int b = dstv[v] >> 10;
            const int pos = atomicAdd(&cur[b], 1);
            tmp_sd[pos] = make_int2(ei[e], dstv[v]);
            const float4* e4 = (const float4*)(ea + (size_t)e * EDIM);
            float4 a = e4[0], bb = e4[1];
            uint4 u;
            u.x = (u32)f2bf(a.x) | ((u32)f2bf(a.y) << 16);
            u.y = (u32)f2bf(a.z) | ((u32)f2bf(a.w) << 16);
            u.z = (u32)f2bf(bb.x) | ((u32)f2bf(bb.y) << 16);
            u.w = (u32)f2bf(bb.z) | ((u32)f2bf(bb.w) << 16);
            tmp_eab[pos] = u;
        }
    }
}

// ---- phase 2: in-bucket scatter to final CSR position ----------------------
__global__ __launch_bounds__(256) void p2_kernel(
    const int2* __restrict__ tmp_sd, const uint4* __restrict__ tmp_eab,
    int* __restrict__ cursor,
    int2* __restrict__ perm2, uint4* __restrict__ eab)
{
    const int base = blockIdx.x * EPB;
    const int t = threadIdx.x;
#pragma unroll
    for (int v = 0; v < VPT; ++v) {
        const int i = base + v * 256 + t;
        if (i < NE) {
            const int2 sd = tmp_sd[i];
            const int pos = atomicAdd(&cursor[sd.y], 1);
            perm2[pos] = sd;
            eab[pos] = tmp_eab[i];
        }
    }
}

// ---- edge-centric aggregation: one wave per 16 consecutive CSR edges -------
__global__ __launch_bounds__(256) void aggr_kernel(
    const int2* __restrict__ perm2,
    const u32* __restrict__ eab32,
    const float* __restrict__ We, const float* __restrict__ be,
    const u16* __restrict__ h16, float* __restrict__ h)
{
    const int lane = threadIdx.x & 63;
    const int chunk = blockIdx.x * 4 + (threadIdx.x >> 6);
    const int base = chunk * EPW;

    float we_r[EDIM];
#pragma unroll
    for (int d = 0; d < EDIM; ++d) we_r[d] = We[d * H + lane];
    const float be_r = be[lane];

    const int2 pd = perm2[base + (lane & 15)];
    const u32 eu = eab32[(size_t)base * 4 + lane];

    float hv[EPW];
#pragma unroll
    for (int j = 0; j < EPW; ++j) {
        const int sj = __builtin_amdgcn_readlane(pd.x, j);
        hv[j] = bf2f(h16[(size_t)sj * H + lane]);
    }

    float acc = 0.0f;
    int cur = __builtin_amdgcn_readlane(pd.y, 0);
#pragma unroll
    for (int j = 0; j < EPW; ++j) {
        const int dj = __builtin_amdgcn_readlane(pd.y, j);
        float msg = be_r;
#pragma unroll
        for (int p = 0; p < 4; ++p) {
            const u32 w2 = __builtin_amdgcn_readlane(eu, j * 4 + p);
            msg = fmaf(__uint_as_float(w2 << 16), we_r[2 * p], msg);
            msg = fmaf(__uint_as_float(w2 & 0xffff0000u), we_r[2 * p + 1], msg);
        }
        if (dj != cur) {                       // wave-uniform branch
            unsafeAtomicAdd(&h[(size_t)cur * H + lane], acc);
            acc = 0.0f;
            cur = dj;
        }
        acc += fmaxf(hv[j] + msg, 0.0f);
    }
    unsafeAtomicAdd(&h[(size_t)cur * H + lane], acc);
}

// ---------------- node MLP (in place): thread-per-node, scalar weights ------
__global__ __launch_bounds__(MLPB) void node_mlp_kernel(
    const float* __restrict__ W1, const float* __restrict__ b1,
    const float* __restrict__ W2, const float* __restrict__ b2,
    float* __restrict__ h)
{
    __shared__ float ts[MLPB * 65];
    const int t = threadIdx.x;
    const int n = blockIdx.x * MLPB + t;
    if (n >= NN) return;
    float* hrow = h + (size_t)n * H;

    float acc[H];
#pragma unroll
    for (int d = 0; d < H; ++d) acc[d] = b1[d];
    for (int k4 = 0; k4 < H / 4; ++k4) {
        const float4 zc = ((const float4*)hrow)[k4];
        const float* w = W1 + (size_t)k4 * 4 * H;
#pragma unroll
        for (int d = 0; d < H; ++d) acc[d] = fmaf(zc.x, w[d], acc[d]);
#pragma unroll
        for (int d = 0; d < H; ++d) acc[d] = fmaf(zc.y, w[H + d], acc[d]);
#pragma unroll
        for (int d = 0; d < H; ++d) acc[d] = fmaf(zc.z, w[2 * H + d], acc[d]);
#pragma unroll
        for (int d = 0; d < H; ++d) acc[d] = fmaf(zc.w, w[3 * H + d], acc[d]);
    }
#pragma unroll
    for (int d = 0; d < H; ++d) ts[t * 65 + d] = fmaxf(acc[d], 0.0f);

#pragma unroll
    for (int d = 0; d < H; ++d) acc[d] = b2[d];
    for (int k4 = 0; k4 < H / 4; ++k4) {
        const float* w = W2 + (size_t)k4 * 4 * H;
        const float z0 = ts[t * 65 + k4 * 4 + 0];
        const float z1 = ts[t * 65 + k4 * 4 + 1];
        const float z2 = ts[t * 65 + k4 * 4 + 2];
        const float z3 = ts[t * 65 + k4 * 4 + 3];
#pragma unroll
        for (int d = 0; d < H; ++d) acc[d] = fmaf(z0, w[d], acc[d]);
#pragma unroll
        for (int d = 0; d < H; ++d) acc[d] = fmaf(z1, w[H + d], acc[d]);
#pragma unroll
        for (int d = 0; d < H; ++d) acc[d] = fmaf(z2, w[2 * H + d], acc[d]);
#pragma unroll
        for (int d = 0; d < H; ++d) acc[d] = fmaf(z3, w[3 * H + d], acc[d]);
    }
#pragma unroll
    for (int d4 = 0; d4 < H / 4; ++d4)
        ((float4*)hrow)[d4] = make_float4(acc[4 * d4], acc[4 * d4 + 1],
                                          acc[4 * d4 + 2], acc[4 * d4 + 3]);
}

// ------- GraphNorm + relu, in place; refresh h16; optional pool accum -------
__global__ __launch_bounds__(1024) void graphnorm_kernel(
    float* __restrict__ h, u16* __restrict__ h16,
    const int* __restrict__ start,
    const float* __restrict__ w, const float* __restrict__ b,
    const float* __restrict__ a,
    float* __restrict__ pool, int do_pool)
{
    __shared__ float red1[16][H], red2[16][H];
    __shared__ float amean_s[H], rstd_s[H];
    const int g = blockIdx.x;
    const int lane = threadIdx.x & 63;
    const int wv = threadIdx.x >> 6;
    const int s = start[g], e = start[g + 1];

    float s1 = 0.f, s2 = 0.f;
    for (int i = s + wv; i < e; i += 16) {
        float v = h[(size_t)i * H + lane];
        s1 += v; s2 += v * v;
    }
    red1[wv][lane] = s1; red2[wv][lane] = s2;
    __syncthreads();
    if (threadIdx.x < H) {
        float t1 = 0.f, t2 = 0.f;
#pragma unroll
        for (int k = 0; k < 16; ++k) { t1 += red1[k][lane]; t2 += red2[k][lane]; }
        float cnt = fmaxf((float)(e - s), 1.0f);
        float mean = t1 / cnt;
        float alpha = a[lane];
        float var = t2 / cnt - (2.0f * alpha - alpha * alpha) * mean * mean;
        var = fmaxf(var, 0.0f);
        amean_s[lane] = alpha * mean;
        rstd_s[lane] = rsqrtf(var + EPSV);
    }
    __syncthreads();
    const float am = amean_s[lane], rstd = rstd_s[lane];
    const float ww = w[lane], bb = b[lane];
    float ps = 0.f;
    for (int i = s + wv; i < e; i += 16) {
        float v = (h[(size_t)i * H + lane] - am) * rstd * ww + bb;
        v = fmaxf(v, 0.0f);
        h[(size_t)i * H + lane] = v;
        h16[(size_t)i * H + lane] = f2bf(v);
        ps += v;
    }
    if (do_pool && e > s) unsafeAtomicAdd(&pool[g * H + lane], ps);
}

// ---------------- readout from pooled sums ----------------------------------
__global__ __launch_bounds__(64) void final_kernel(
    const float* __restrict__ pool,
    const float* __restrict__ W1, const float* __restrict__ b1,
    const float* __restrict__ W2, const float* __restrict__ b2,
    float* __restrict__ out)
{
    const int g = blockIdx.x;
    const int lane = threadIdx.x;
    const float gv = pool[g * H + lane];
    float acc = b1[lane];
#pragma unroll
    for (int d = 0; d < H; ++d)
        acc = fmaf(__shfl(gv, d, 64), W1[d * H + lane], acc);
    float r = fmaxf(acc, 0.0f);
    float v = r * W2[lane];
#pragma unroll
    for (int o = 32; o > 0; o >>= 1) v += __shfl_xor(v, o, 64);
    if (lane == 0) out[g] = v + b2[0];
}

extern "C" void kernel_launch(void* const* d_in, const int* in_sizes, int n_in,
                              void* d_out, int out_size, void* d_ws, size_t ws_size,
                              hipStream_t stream)
{
    const float* x      = (const float*)d_in[0];
    const int*   ei     = (const int*)  d_in[1];
    const float* ea     = (const float*)d_in[2];
    const int*   batch  = (const int*)  d_in[3];
    const float* ligW1  = (const float*)d_in[4];
    const float* ligb1  = (const float*)d_in[5];
    const float* ligW2  = (const float*)d_in[6];
    const float* ligb2  = (const float*)d_in[7];
    const float* protW1 = (const float*)d_in[8];
    const float* protb1 = (const float*)d_in[9];
    const float* protW2 = (const float*)d_in[10];
    const float* protb2 = (const float*)d_in[11];
    const float* convWe = (const float*)d_in[12];
    const float* convbe = (const float*)d_in[13];
    const float* convW1 = (const float*)d_in[14];
    const float* convb1 = (const float*)d_in[15];
    const float* convW2 = (const float*)d_in[16];
    const float* convb2 = (const float*)d_in[17];
    const float* normw  = (const float*)d_in[18];
    const float* normb  = (const float*)d_in[19];
    const float* norma  = (const float*)d_in[20];
    const float* outW1  = (const float*)d_in[21];
    const float* outb1  = (const float*)d_in[22];
    const float* outW2  = (const float*)d_in[23];
    const float* outb2  = (const float*)d_in[24];

    float* out = (float*)d_out;

    // -------- workspace layout (16B-aligned blocks first) -------------------
    // tmp arrays for the 2-phase fill OVERLAY h and h16 (both dead until enc,
    // which runs after p2).
    float* h         = (float*)d_ws;                    // NN*H f32      25.6 MB
    uint4* eab       = (uint4*)(h + (size_t)NN * H);    // NE uint4      25.6 MB
    int2*  perm2     = (int2*)(eab + (size_t)NE);       // NE int2       12.8 MB
    u16*   h16       = (u16*)(perm2 + (size_t)NE);      // NN*H u16      12.8 MB
    uint4* tmp_eab   = (uint4*)h;                       // NE uint4 (overlay h)
    int2*  tmp_sd    = (int2*)h16;                      // NE int2  (overlay h16)

    int*   deg       = (int*)(h16 + (size_t)NN * H);    // NN   (zeroed)
    int*   ctr       = deg + NN;                        // 2    (zeroed)
    int*   gbcount   = ctr + 2;                         // NB   (zeroed)
    float* pool      = (float*)(gbcount + NB);          // GNUM*H (zeroed)
    int*   row_start = (int*)(pool + GNUM * H);         // NN+1
    int*   cursor    = row_start + (NN + 1);            // NN
    int*   gcur      = cursor + NN;                     // NB
    int*   bsum      = gcur + NB;                       // 512
    int*   start     = bsum + 512;                      // GNUM+1
    int*   nlist     = start + (GNUM + 1);              // NN

    // zero deg, ctr, gbcount, pool in one shot
    hipMemsetAsync(deg, 0, ((size_t)NN + 2 + NB + GNUM * H) * sizeof(int), stream);

    // ---- CSR build (2-phase bucketed fill) ----
    bhist_kernel<<<NBLK_E, 256, 0, stream>>>(ei, deg, gbcount);
    bscan_kernel<<<1, NB, 0, stream>>>(gbcount, gcur);
    scan_a_kernel<<<NBLK_SCAN, 256, 0, stream>>>(deg, row_start, bsum);
    scan_b_kernel<<<1, 512, 0, stream>>>(bsum);
    scan_c_kernel<<<NBLK_SCAN, 256, 0, stream>>>(row_start, bsum, cursor);
    p1_kernel<<<NBLK_E, 256, 0, stream>>>(ei, ea, gcur, tmp_sd, tmp_eab);
    p2_kernel<<<NBLK_E, 256, 0, stream>>>(tmp_sd, tmp_eab, cursor, perm2, eab);

    // ---- encoder (after tmp overlays are dead) ----
    partition_kernel<<<(NN + 255) / 256, 256, 0, stream>>>(x, ctr, nlist);
    const int mlp_blocks = (NN + MLPB - 1) / MLPB;
    enc_kernel<<<mlp_blocks, MLPB, 0, stream>>>(
        nlist, x, ligW1, ligb1, ligW2, ligb2, protW1, protb1, protW2, protb2, h, h16);

    bounds_kernel<<<2, 256, 0, stream>>>(batch, start);

    const int aggr_blocks = NE / EPW / 4;   // 25000, exact
    for (int l = 0; l < 3; ++l) {
        aggr_kernel<<<aggr_blocks, 256, 0, stream>>>(
            perm2, (const u32*)eab,
            convWe + (size_t)l * EDIM * H, convbe + (size_t)l * H, h16, h);
        node_mlp_kernel<<<mlp_blocks, MLPB, 0, stream>>>(
            convW1 + (size_t)l * H * H, convb1 + (size_t)l * H,
            convW2 + (size_t)l * H * H, convb2 + (size_t)l * H, h);
        graphnorm_kernel<<<GNUM, 1024, 0, stream>>>(
            h, h16, start, normw + (size_t)l * H, normb + (size_t)l * H,
            norma + (size_t)l * H, pool, (l == 2) ? 1 : 0);
    }
    final_kernel<<<GNUM, 64, 0, stream>>>(pool, outW1, outb1, outW2, outb2, out);
}

// Round 8
// 866.677 us; speedup vs baseline: 1.0919x; 1.0827x over previous
//
#include <hip/hip_runtime.h>

#define NN 100000   // nodes
#define NE 1600000  // edges
#define IN_CH 41
#define EDIM 8
#define H 64
#define GNUM 256
#define ATOM 21
#define EPSV 1e-5f
#define EPW 16      // edges per wave in aggr (NE % EPW == 0)
#define MLPB 64     // threads per block in thread-per-node MLPs (1 wave)

#define NB 128      // dst buckets (dst>>10 -> 0..97)
#define VPT 8       // edges per thread in bucket kernels
#define EPB (256 * VPT)                    // 2048 edges per block
#define NBLK_E ((NE + EPB - 1) / EPB)      // 782
#define NBLK_SCAN ((NN + 255) / 256)       // 391

typedef unsigned short u16;
typedef unsigned int u32;
typedef unsigned long long u64;

__device__ __forceinline__ u16 f2bf(float f) {
    u32 u = __float_as_uint(f);
    u32 r = (u + 0x7FFFu + ((u >> 16) & 1u)) >> 16;   // RNE
    return (u16)r;
}
__device__ __forceinline__ float bf2f(u16 u) {
    return __uint_as_float(((u32)u) << 16);
}

// ---- partition: mask per node -> one compacted list (lig front, prot back) -
__global__ __launch_bounds__(256) void partition_kernel(
    const float* __restrict__ x, int* __restrict__ ctr,   // ctr[0]=lig, ctr[1]=prot
    int* __restrict__ nlist)
{
    const int n = blockIdx.x * 256 + threadIdx.x;
    const int lane = threadIdx.x & 63;
    float m = 0.0f;
    if (n < NN) {
        const float* xr = x + (size_t)n * IN_CH + ATOM;
#pragma unroll
        for (int d = 0; d < IN_CH - ATOM; ++d) m += fabsf(xr[d]);
    }
    const bool valid = n < NN;
    const bool prot = valid && (m > 1e-6f);
    const bool lig = valid && !prot;

    const u64 bl = __ballot(lig);
    const u64 bp = __ballot(prot);
    const u64 below_m = (lane == 63) ? (~0ull >> 1) : ((1ull << lane) - 1ull);
    int base_l = 0, base_p = 0;
    if (lane == 0) {
        if (bl) base_l = atomicAdd(&ctr[0], (int)__popcll(bl));
        if (bp) base_p = atomicAdd(&ctr[1], (int)__popcll(bp));
    }
    base_l = __shfl(base_l, 0, 64);
    base_p = __shfl(base_p, 0, 64);
    if (lig)  nlist[base_l + (int)__popcll(bl & below_m)] = n;
    if (prot) nlist[NN - 1 - (base_p + (int)__popcll(bp & below_m))] = n | 0x80000000;
}

// ---- encoder MLP body: thread-per-node, chunked register preload -----------
__device__ __forceinline__ void enc_body(
    int n, const float* __restrict__ x,
    const float* __restrict__ W1, const float* __restrict__ b1,
    const float* __restrict__ W2, const float* __restrict__ b2,
    float* __restrict__ h, u16* __restrict__ h16, float* __restrict__ ts)
{
    const float* xrow = x + (size_t)n * IN_CH;
    float acc[H];
#pragma unroll
    for (int d = 0; d < H; ++d) acc[d] = b1[d];
    // chunks of 8: preload 8 x-values (independent loads), then 512 FMAs
    for (int kc = 0; kc < 40; kc += 8) {
        float xv[8];
#pragma unroll
        for (int j = 0; j < 8; ++j) xv[j] = xrow[kc + j];
#pragma unroll
        for (int j = 0; j < 8; ++j) {
            const float* w = W1 + (size_t)(kc + j) * H;
#pragma unroll
            for (int d = 0; d < H; ++d) acc[d] = fmaf(xv[j], w[d], acc[d]);
        }
    }
    {   // tail k = 40
        const float xv = xrow[40];
        const float* w = W1 + (size_t)40 * H;
#pragma unroll
        for (int d = 0; d < H; ++d) acc[d] = fmaf(xv, w[d], acc[d]);
    }
#pragma unroll
    for (int d = 0; d < H; ++d) ts[d] = fmaxf(acc[d], 0.0f);

#pragma unroll
    for (int d = 0; d < H; ++d) acc[d] = b2[d];
    for (int k4 = 0; k4 < H / 4; ++k4) {
        const float* w = W2 + (size_t)k4 * 4 * H;
        const float z0 = ts[k4 * 4 + 0];
        const float z1 = ts[k4 * 4 + 1];
        const float z2 = ts[k4 * 4 + 2];
        const float z3 = ts[k4 * 4 + 3];
#pragma unroll
        for (int d = 0; d < H; ++d) acc[d] = fmaf(z0, w[d], acc[d]);
#pragma unroll
        for (int d = 0; d < H; ++d) acc[d] = fmaf(z1, w[H + d], acc[d]);
#pragma unroll
        for (int d = 0; d < H; ++d) acc[d] = fmaf(z2, w[2 * H + d], acc[d]);
#pragma unroll
        for (int d = 0; d < H; ++d) acc[d] = fmaf(z3, w[3 * H + d], acc[d]);
    }
    float* hrow = h + (size_t)n * H;
    u32* h16row = (u32*)(h16 + (size_t)n * H);
#pragma unroll
    for (int d4 = 0; d4 < H / 4; ++d4) {
        float v0 = fmaxf(acc[4 * d4 + 0], 0.0f);
        float v1 = fmaxf(acc[4 * d4 + 1], 0.0f);
        float v2 = fmaxf(acc[4 * d4 + 2], 0.0f);
        float v3 = fmaxf(acc[4 * d4 + 3], 0.0f);
        ((float4*)hrow)[d4] = make_float4(v0, v1, v2, v3);
        h16row[2 * d4 + 0] = (u32)f2bf(v0) | ((u32)f2bf(v1) << 16);
        h16row[2 * d4 + 1] = (u32)f2bf(v2) | ((u32)f2bf(v3) << 16);
    }
}

// one dispatch; waves are type-uniform except the single lig/prot boundary
__global__ __launch_bounds__(MLPB) void enc_kernel(
    const int* __restrict__ nlist, const float* __restrict__ x,
    const float* __restrict__ lW1, const float* __restrict__ lb1,
    const float* __restrict__ lW2, const float* __restrict__ lb2,
    const float* __restrict__ pW1, const float* __restrict__ pb1,
    const float* __restrict__ pW2, const float* __restrict__ pb2,
    float* __restrict__ h, u16* __restrict__ h16)
{
    __shared__ float ts[MLPB * 65];
    const int t = threadIdx.x;
    const int i = blockIdx.x * MLPB + t;
    if (i >= NN) return;
    const int raw = nlist[i];
    const bool prot = raw < 0;
    const int n = raw & 0x7fffffff;
    float* myts = &ts[t * 65];
    if (__any(!prot)) {
        if (!prot) enc_body(n, x, lW1, lb1, lW2, lb2, h, h16, myts);
    }
    if (__any(prot)) {
        if (prot) enc_body(n, x, pW1, pb1, pW2, pb2, h, h16, myts);
    }
}

// ---------------- per-graph node ranges (batch is sorted) -------------------
__global__ void bounds_kernel(const int* __restrict__ batch, int* __restrict__ start)
{
    int g = blockIdx.x * blockDim.x + threadIdx.x;
    if (g > GNUM) return;
    int lo = 0, hi = NN;
    while (lo < hi) {
        int mid = (lo + hi) >> 1;
        if (batch[mid] < g) lo = mid + 1; else hi = mid;
    }
    start[g] = lo;
}

// ---- bucket+degree histogram: deg[dst]++ (global) + bucket counts ----------
__global__ __launch_bounds__(256) void bhist_kernel(
    const int* __restrict__ ei, int* __restrict__ deg, int* __restrict__ gbcount)
{
    __shared__ int cnt[NB];
    const int t = threadIdx.x;
    if (t < NB) cnt[t] = 0;
    __syncthreads();
    const int base = blockIdx.x * EPB;
#pragma unroll
    for (int v = 0; v < VPT; ++v) {
        const int e = base + v * 256 + t;
        if (e < NE) {
            const int d = ei[NE + e];
            atomicAdd(&deg[d], 1);
            atomicAdd(&cnt[d >> 10], 1);
        }
    }
    __syncthreads();
    if (t < NB && cnt[t]) atomicAdd(&gbcount[t], cnt[t]);
}

// ---- exclusive scan of the 128 bucket counts -> gcur -----------------------
__global__ __launch_bounds__(NB) void bscan_kernel(
    const int* __restrict__ gbcount, int* __restrict__ gcur)
{
    __shared__ int s[NB];
    const int t = threadIdx.x;
    const int v = gbcount[t];
    s[t] = v;
    __syncthreads();
#pragma unroll
    for (int off = 1; off < NB; off <<= 1) {
        int tmp = (t >= off) ? s[t - off] : 0;
        __syncthreads();
        s[t] += tmp;
        __syncthreads();
    }
    gcur[t] = s[t] - v;
}

// ---------------- node-degree scans (row_start, cursor) ---------------------
__global__ __launch_bounds__(256) void scan_a_kernel(
    const int* __restrict__ deg, int* __restrict__ row_start, int* __restrict__ bsum)
{
    __shared__ int s[256];
    const int t = threadIdx.x;
    const int idx = blockIdx.x * 256 + t;
    int v = (idx < NN) ? deg[idx] : 0;
    s[t] = v;
    __syncthreads();
#pragma unroll
    for (int off = 1; off < 256; off <<= 1) {
        int tmp = (t >= off) ? s[t - off] : 0;
        __syncthreads();
        s[t] += tmp;
        __syncthreads();
    }
    if (idx < NN) row_start[idx] = s[t] - v;  // exclusive
    if (t == 255) bsum[blockIdx.x] = s[255];
}

__global__ __launch_bounds__(512) void scan_b_kernel(int* __restrict__ bsum)
{
    __shared__ int s[512];
    const int t = threadIdx.x;
    int v = (t < NBLK_SCAN) ? bsum[t] : 0;
    s[t] = v;
    __syncthreads();
#pragma unroll
    for (int off = 1; off < 512; off <<= 1) {
        int tmp = (t >= off) ? s[t - off] : 0;
        __syncthreads();
        s[t] += tmp;
        __syncthreads();
    }
    if (t < NBLK_SCAN) bsum[t] = s[t] - v;  // exclusive
}

__global__ __launch_bounds__(256) void scan_c_kernel(
    int* __restrict__ row_start, const int* __restrict__ bsum, int* __restrict__ cursor)
{
    const int idx = blockIdx.x * 256 + threadIdx.x;
    if (idx < NN) {
        int rs = row_start[idx] + bsum[blockIdx.x];
        row_start[idx] = rs;
        cursor[idx] = rs;
    } else if (idx == NN) {
        row_start[NN] = NE;
    }
}

// ---- phase 1: LDS-ranked bucket partition, coalesced run writes ------------
__global__ __launch_bounds__(256) void p1_kernel(
    const int* __restrict__ ei, const float* __restrict__ ea,
    int* __restrict__ gcur,
    int2* __restrict__ tmp_sd, uint4* __restrict__ tmp_eab)
{
    __shared__ int cnt[NB];
    __shared__ int cur[NB];
    const int t = threadIdx.x;
    if (t < NB) cnt[t] = 0;
    __syncthreads();
    const int base = blockIdx.x * EPB;
    int dstv[VPT];
#pragma unroll
    for (int v = 0; v < VPT; ++v) {
        const int e = base + v * 256 + t;
        dstv[v] = -1;
        if (e < NE) {
            dstv[v] = ei[NE + e];
            atomicAdd(&cnt[dstv[v] >> 10], 1);
        }
    }
    __syncthreads();
    if (t < NB) cur[t] = cnt[t] ? atomicAdd(&gcur[t], cnt[t]) : 0;
    __syncthreads();
#pragma unroll
    for (int v = 0; v < VPT; ++v) {
        const int e = base + v * 256 + t;
        if (e < NE) {
            const int b = dstv[v] >> 10;
            const int pos = atomicAdd(&cur[b], 1);
            tmp_sd[pos] = make_int2(ei[e], dstv[v]);
            const float4* e4 = (const float4*)(ea + (size_t)e * EDIM);
            float4 a = e4[0], bb = e4[1];
            uint4 u;
            u.x = (u32)f2bf(a.x) | ((u32)f2bf(a.y) << 16);
            u.y = (u32)f2bf(a.z) | ((u32)f2bf(a.w) << 16);
            u.z = (u32)f2bf(bb.x) | ((u32)f2bf(bb.y) << 16);
            u.w = (u32)f2bf(bb.z) | ((u32)f2bf(bb.w) << 16);
            tmp_eab[pos] = u;
        }
    }
}

// ---- phase 2: in-bucket scatter to final CSR position ----------------------
__global__ __launch_bounds__(256) void p2_kernel(
    const int2* __restrict__ tmp_sd, const uint4* __restrict__ tmp_eab,
    int* __restrict__ cursor,
    int2* __restrict__ perm2, uint4* __restrict__ eab)
{
    const int base = blockIdx.x * EPB;
    const int t = threadIdx.x;
#pragma unroll
    for (int v = 0; v < VPT; ++v) {
        const int i = base + v * 256 + t;
        if (i < NE) {
            const int2 sd = tmp_sd[i];
            const int pos = atomicAdd(&cursor[sd.y], 1);
            perm2[pos] = sd;
            eab[pos] = tmp_eab[i];
        }
    }
}

// ---- edge-centric aggregation: one wave per 16 consecutive CSR edges -------
__global__ __launch_bounds__(256) void aggr_kernel(
    const int2* __restrict__ perm2,
    const u32* __restrict__ eab32,
    const float* __restrict__ We, const float* __restrict__ be,
    const u16* __restrict__ h16, float* __restrict__ h)
{
    const int lane = threadIdx.x & 63;
    const int chunk = blockIdx.x * 4 + (threadIdx.x >> 6);
    const int base = chunk * EPW;

    float we_r[EDIM];
#pragma unroll
    for (int d = 0; d < EDIM; ++d) we_r[d] = We[d * H + lane];
    const float be_r = be[lane];

    const int2 pd = perm2[base + (lane & 15)];
    const u32 eu = eab32[(size_t)base * 4 + lane];

    float hv[EPW];
#pragma unroll
    for (int j = 0; j < EPW; ++j) {
        const int sj = __builtin_amdgcn_readlane(pd.x, j);
        hv[j] = bf2f(h16[(size_t)sj * H + lane]);
    }

    float acc = 0.0f;
    int cur = __builtin_amdgcn_readlane(pd.y, 0);
#pragma unroll
    for (int j = 0; j < EPW; ++j) {
        const int dj = __builtin_amdgcn_readlane(pd.y, j);
        float msg = be_r;
#pragma unroll
        for (int p = 0; p < 4; ++p) {
            const u32 w2 = __builtin_amdgcn_readlane(eu, j * 4 + p);
            msg = fmaf(__uint_as_float(w2 << 16), we_r[2 * p], msg);
            msg = fmaf(__uint_as_float(w2 & 0xffff0000u), we_r[2 * p + 1], msg);
        }
        if (dj != cur) {                       // wave-uniform branch
            unsafeAtomicAdd(&h[(size_t)cur * H + lane], acc);
            acc = 0.0f;
            cur = dj;
        }
        acc += fmaxf(hv[j] + msg, 0.0f);
    }
    unsafeAtomicAdd(&h[(size_t)cur * H + lane], acc);
}

// ---------------- node MLP (in place): thread-per-node, chunked preload -----
__global__ __launch_bounds__(MLPB) void node_mlp_kernel(
    const float* __restrict__ W1, const float* __restrict__ b1,
    const float* __restrict__ W2, const float* __restrict__ b2,
    float* __restrict__ h)
{
    __shared__ float ts[MLPB * 65];
    const int t = threadIdx.x;
    const int n = blockIdx.x * MLPB + t;
    if (n >= NN) return;
    float* hrow = h + (size_t)n * H;

    float acc[H];
#pragma unroll
    for (int d = 0; d < H; ++d) acc[d] = b1[d];
    // chunks of 4 float4 (16 values): preload, then 1024 FMAs
    for (int kc = 0; kc < H / 4; kc += 4) {
        float4 z4[4];
#pragma unroll
        for (int j = 0; j < 4; ++j) z4[j] = ((const float4*)hrow)[kc + j];
#pragma unroll
        for (int j = 0; j < 4; ++j) {
            const float* w = W1 + (size_t)(kc + j) * 4 * H;
#pragma unroll
            for (int d = 0; d < H; ++d) acc[d] = fmaf(z4[j].x, w[d], acc[d]);
#pragma unroll
            for (int d = 0; d < H; ++d) acc[d] = fmaf(z4[j].y, w[H + d], acc[d]);
#pragma unroll
            for (int d = 0; d < H; ++d) acc[d] = fmaf(z4[j].z, w[2 * H + d], acc[d]);
#pragma unroll
            for (int d = 0; d < H; ++d) acc[d] = fmaf(z4[j].w, w[3 * H + d], acc[d]);
        }
    }
#pragma unroll
    for (int d = 0; d < H; ++d) ts[t * 65 + d] = fmaxf(acc[d], 0.0f);

#pragma unroll
    for (int d = 0; d < H; ++d) acc[d] = b2[d];
    for (int k4 = 0; k4 < H / 4; ++k4) {
        const float* w = W2 + (size_t)k4 * 4 * H;
        const float z0 = ts[t * 65 + k4 * 4 + 0];
        const float z1 = ts[t * 65 + k4 * 4 + 1];
        const float z2 = ts[t * 65 + k4 * 4 + 2];
        const float z3 = ts[t * 65 + k4 * 4 + 3];
#pragma unroll
        for (int d = 0; d < H; ++d) acc[d] = fmaf(z0, w[d], acc[d]);
#pragma unroll
        for (int d = 0; d < H; ++d) acc[d] = fmaf(z1, w[H + d], acc[d]);
#pragma unroll
        for (int d = 0; d < H; ++d) acc[d] = fmaf(z2, w[2 * H + d], acc[d]);
#pragma unroll
        for (int d = 0; d < H; ++d) acc[d] = fmaf(z3, w[3 * H + d], acc[d]);
    }
#pragma unroll
    for (int d4 = 0; d4 < H / 4; ++d4)
        ((float4*)hrow)[d4] = make_float4(acc[4 * d4], acc[4 * d4 + 1],
                                          acc[4 * d4 + 2], acc[4 * d4 + 3]);
}

// ------- GraphNorm + relu, in place; refresh h16; optional pool accum -------
__global__ __launch_bounds__(1024) void graphnorm_kernel(
    float* __restrict__ h, u16* __restrict__ h16,
    const int* __restrict__ start,
    const float* __restrict__ w, const float* __restrict__ b,
    const float* __restrict__ a,
    float* __restrict__ pool, int do_pool)
{
    __shared__ float red1[16][H], red2[16][H];
    __shared__ float amean_s[H], rstd_s[H];
    const int g = blockIdx.x;
    const int lane = threadIdx.x & 63;
    const int wv = threadIdx.x >> 6;
    const int s = start[g], e = start[g + 1];

    float s1 = 0.f, s2 = 0.f;
    for (int i = s + wv; i < e; i += 16) {
        float v = h[(size_t)i * H + lane];
        s1 += v; s2 += v * v;
    }
    red1[wv][lane] = s1; red2[wv][lane] = s2;
    __syncthreads();
    if (threadIdx.x < H) {
        float t1 = 0.f, t2 = 0.f;
#pragma unroll
        for (int k = 0; k < 16; ++k) { t1 += red1[k][lane]; t2 += red2[k][lane]; }
        float cnt = fmaxf((float)(e - s), 1.0f);
        float mean = t1 / cnt;
        float alpha = a[lane];
        float var = t2 / cnt - (2.0f * alpha - alpha * alpha) * mean * mean;
        var = fmaxf(var, 0.0f);
        amean_s[lane] = alpha * mean;
        rstd_s[lane] = rsqrtf(var + EPSV);
    }
    __syncthreads();
    const float am = amean_s[lane], rstd = rstd_s[lane];
    const float ww = w[lane], bb = b[lane];
    float ps = 0.f;
    for (int i = s + wv; i < e; i += 16) {
        float v = (h[(size_t)i * H + lane] - am) * rstd * ww + bb;
        v = fmaxf(v, 0.0f);
        h[(size_t)i * H + lane] = v;
        h16[(size_t)i * H + lane] = f2bf(v);
        ps += v;
    }
    if (do_pool && e > s) unsafeAtomicAdd(&pool[g * H + lane], ps);
}

// ---------------- readout from pooled sums ----------------------------------
__global__ __launch_bounds__(64) void final_kernel(
    const float* __restrict__ pool,
    const float* __restrict__ W1, const float* __restrict__ b1,
    const float* __restrict__ W2, const float* __restrict__ b2,
    float* __restrict__ out)
{
    const int g = blockIdx.x;
    const int lane = threadIdx.x;
    const float gv = pool[g * H + lane];
    float acc = b1[lane];
#pragma unroll
    for (int d = 0; d < H; ++d)
        acc = fmaf(__shfl(gv, d, 64), W1[d * H + lane], acc);
    float r = fmaxf(acc, 0.0f);
    float v = r * W2[lane];
#pragma unroll
    for (int o = 32; o > 0; o >>= 1) v += __shfl_xor(v, o, 64);
    if (lane == 0) out[g] = v + b2[0];
}

extern "C" void kernel_launch(void* const* d_in, const int* in_sizes, int n_in,
                              void* d_out, int out_size, void* d_ws, size_t ws_size,
                              hipStream_t stream)
{
    const float* x      = (const float*)d_in[0];
    const int*   ei     = (const int*)  d_in[1];
    const float* ea     = (const float*)d_in[2];
    const int*   batch  = (const int*)  d_in[3];
    const float* ligW1  = (const float*)d_in[4];
    const float* ligb1  = (const float*)d_in[5];
    const float* ligW2  = (const float*)d_in[6];
    const float* ligb2  = (const float*)d_in[7];
    const float* protW1 = (const float*)d_in[8];
    const float* protb1 = (const float*)d_in[9];
    const float* protW2 = (const float*)d_in[10];
    const float* protb2 = (const float*)d_in[11];
    const float* convWe = (const float*)d_in[12];
    const float* convbe = (const float*)d_in[13];
    const float* convW1 = (const float*)d_in[14];
    const float* convb1 = (const float*)d_in[15];
    const float* convW2 = (const float*)d_in[16];
    const float* convb2 = (const float*)d_in[17];
    const float* normw  = (const float*)d_in[18];
    const float* normb  = (const float*)d_in[19];
    const float* norma  = (const float*)d_in[20];
    const float* outW1  = (const float*)d_in[21];
    const float* outb1  = (const float*)d_in[22];
    const float* outW2  = (const float*)d_in[23];
    const float* outb2  = (const float*)d_in[24];

    float* out = (float*)d_out;

    // -------- workspace layout (16B-aligned blocks first) -------------------
    float* h         = (float*)d_ws;                    // NN*H f32      25.6 MB
    uint4* eab       = (uint4*)(h + (size_t)NN * H);    // NE uint4      25.6 MB
    int2*  perm2     = (int2*)(eab + (size_t)NE);       // NE int2       12.8 MB
    u16*   h16       = (u16*)(perm2 + (size_t)NE);      // NN*H u16      12.8 MB
    uint4* tmp_eab   = (uint4*)h;                       // NE uint4 (overlay h)
    int2*  tmp_sd    = (int2*)h16;                      // NE int2  (overlay h16)

    int*   deg       = (int*)(h16 + (size_t)NN * H);    // NN   (zeroed)
    int*   ctr       = deg + NN;                        // 2    (zeroed)
    int*   gbcount   = ctr + 2;                         // NB   (zeroed)
    float* pool      = (float*)(gbcount + NB);          // GNUM*H (zeroed)
    int*   row_start = (int*)(pool + GNUM * H);         // NN+1
    int*   cursor    = row_start + (NN + 1);            // NN
    int*   gcur      = cursor + NN;                     // NB
    int*   bsum      = gcur + NB;                       // 512
    int*   start     = bsum + 512;                      // GNUM+1
    int*   nlist     = start + (GNUM + 1);              // NN

    hipMemsetAsync(deg, 0, ((size_t)NN + 2 + NB + GNUM * H) * sizeof(int), stream);

    // ---- CSR build (2-phase bucketed fill) ----
    bhist_kernel<<<NBLK_E, 256, 0, stream>>>(ei, deg, gbcount);
    bscan_kernel<<<1, NB, 0, stream>>>(gbcount, gcur);
    scan_a_kernel<<<NBLK_SCAN, 256, 0, stream>>>(deg, row_start, bsum);
    scan_b_kernel<<<1, 512, 0, stream>>>(bsum);
    scan_c_kernel<<<NBLK_SCAN, 256, 0, stream>>>(row_start, bsum, cursor);
    p1_kernel<<<NBLK_E, 256, 0, stream>>>(ei, ea, gcur, tmp_sd, tmp_eab);
    p2_kernel<<<NBLK_E, 256, 0, stream>>>(tmp_sd, tmp_eab, cursor, perm2, eab);

    // ---- encoder (after tmp overlays are dead) ----
    partition_kernel<<<(NN + 255) / 256, 256, 0, stream>>>(x, ctr, nlist);
    const int mlp_blocks = (NN + MLPB - 1) / MLPB;
    enc_kernel<<<mlp_blocks, MLPB, 0, stream>>>(
        nlist, x, ligW1, ligb1, ligW2, ligb2, protW1, protb1, protW2, protb2, h, h16);

    bounds_kernel<<<2, 256, 0, stream>>>(batch, start);

    const int aggr_blocks = NE / EPW / 4;   // 25000, exact
    for (int l = 0; l < 3; ++l) {
        aggr_kernel<<<aggr_blocks, 256, 0, stream>>>(
            perm2, (const u32*)eab,
            convWe + (size_t)l * EDIM * H, convbe + (size_t)l * H, h16, h);
        node_mlp_kernel<<<mlp_blocks, MLPB, 0, stream>>>(
            convW1 + (size_t)l * H * H, convb1 + (size_t)l * H,
            convW2 + (size_t)l * H * H, convb2 + (size_t)l * H, h);
        graphnorm_kernel<<<GNUM, 1024, 0, stream>>>(
            h, h16, start, normw + (size_t)l * H, normb + (size_t)l * H,
            norma + (size_t)l * H, pool, (l == 2) ? 1 : 0);
    }
    final_kernel<<<GNUM, 64, 0, stream>>>(pool, outW1, outb1, outW2, outb2, out);
}

// Round 9
// 713.642 us; speedup vs baseline: 1.3260x; 1.2144x over previous
//
#include <hip/hip_runtime.h>

#define NN 100000   // nodes
#define NE 1600000  // edges
#define IN_CH 41
#define EDIM 8
#define H 64
#define GNUM 256
#define ATOM 21
#define EPSV 1e-5f
#define EPW 16      // edges per wave in aggr (NE % EPW == 0)
#define NTILE (NN / 16)   // 6250 node tiles (exact)

#define NB 128      // dst buckets (dst>>10 -> 0..97)
#define VPT 8       // edges per thread in bucket kernels
#define EPB (256 * VPT)                    // 2048 edges per block
#define NBLK_E ((NE + EPB - 1) / EPB)      // 782
#define NBLK_SCAN ((NN + 255) / 256)       // 391

typedef unsigned short u16;
typedef unsigned int u32;
typedef unsigned long long u64;
typedef __attribute__((ext_vector_type(8))) short short8;
typedef __attribute__((ext_vector_type(4))) float floatx4;

__device__ __forceinline__ u16 f2bf(float f) {
    u32 u = __float_as_uint(f);
    u32 r = (u + 0x7FFFu + ((u >> 16) & 1u)) >> 16;   // RNE
    return (u16)r;
}
__device__ __forceinline__ float bf2f(u16 u) {
    return __uint_as_float(((u32)u) << 16);
}
__device__ __forceinline__ floatx4 mfma16(short8 a, short8 b, floatx4 c) {
    return __builtin_amdgcn_mfma_f32_16x16x32_bf16(a, b, c, 0, 0, 0);
}
__device__ __forceinline__ short8 pack_bf8(float4 a, float4 b) {
    short8 s;
    s[0] = (short)f2bf(a.x); s[1] = (short)f2bf(a.y);
    s[2] = (short)f2bf(a.z); s[3] = (short)f2bf(a.w);
    s[4] = (short)f2bf(b.x); s[5] = (short)f2bf(b.y);
    s[6] = (short)f2bf(b.z); s[7] = (short)f2bf(b.w);
    return s;
}

// ---- partition: mask per node -> lig_list / prot_list ----------------------
__global__ __launch_bounds__(256) void partition_kernel(
    const float* __restrict__ x, int* __restrict__ ctr,   // ctr[0]=lig, ctr[1]=prot
    int* __restrict__ lig_list, int* __restrict__ prot_list)
{
    const int n = blockIdx.x * 256 + threadIdx.x;
    const int lane = threadIdx.x & 63;
    float m = 0.0f;
    if (n < NN) {
        const float* xr = x + (size_t)n * IN_CH + ATOM;
#pragma unroll
        for (int d = 0; d < IN_CH - ATOM; ++d) m += fabsf(xr[d]);
    }
    const bool valid = n < NN;
    const bool prot = valid && (m > 1e-6f);
    const bool lig = valid && !prot;

    const u64 bl = __ballot(lig);
    const u64 bp = __ballot(prot);
    const u64 below_m = (lane == 63) ? (~0ull >> 1) : ((1ull << lane) - 1ull);
    int base_l = 0, base_p = 0;
    if (lane == 0) {
        if (bl) base_l = atomicAdd(&ctr[0], (int)__popcll(bl));
        if (bp) base_p = atomicAdd(&ctr[1], (int)__popcll(bp));
    }
    base_l = __shfl(base_l, 0, 64);
    base_p = __shfl(base_p, 0, 64);
    if (lig)  lig_list [base_l + (int)__popcll(bl & below_m)] = n;
    if (prot) prot_list[base_p + (int)__popcll(bp & below_m)] = n;
}

// ---- xb: zero-padded bf16 copy of x [NN x 64] ------------------------------
__global__ __launch_bounds__(256) void xb_kernel(
    const float* __restrict__ x, u16* __restrict__ xb)
{
    const int id = blockIdx.x * 256 + threadIdx.x;
    if (id >= NN * H) return;
    const int n = id >> 6, d = id & 63;
    xb[id] = (d < IN_CH) ? f2bf(x[(size_t)n * IN_CH + d]) : (u16)0;
}

// ---- prep: swizzle 10 weight matrices into MFMA B-fragment order -----------
// dst[id]: id = mat*4096 + ((c*4+t)*64 + lane)*8 + j ; element W[k][n],
// k = c*32 + (lane>>4)*8 + j, n = t*16 + (lane&15); zero-pad k >= K.
__global__ __launch_bounds__(256) void prep_w_kernel(
    const float* __restrict__ ligW1, const float* __restrict__ ligW2,
    const float* __restrict__ protW1, const float* __restrict__ protW2,
    const float* __restrict__ convW1, const float* __restrict__ convW2,
    u16* __restrict__ wf)
{
    const int id = blockIdx.x * 256 + threadIdx.x;
    if (id >= 10 * 4096) return;
    const int j = id & 7, l = (id >> 3) & 63, t = (id >> 9) & 3;
    const int c = (id >> 11) & 1, mat = id >> 12;
    const int k = c * 32 + ((l >> 4) * 8) + j;
    const int n = t * 16 + (l & 15);
    const float* src; int K = 64;
    if (mat == 0)      { src = ligW1;  K = IN_CH; }
    else if (mat == 1) { src = ligW2; }
    else if (mat == 2) { src = protW1; K = IN_CH; }
    else if (mat == 3) { src = protW2; }
    else {
        const int layer = (mat - 4) >> 1;
        src = (((mat - 4) & 1) ? convW2 : convW1) + (size_t)layer * H * H;
    }
    wf[id] = (k < K) ? f2bf(src[(size_t)k * H + n]) : (u16)0;
}

// ---- MFMA MLP over a gathered node list (encoder) --------------------------
__global__ __launch_bounds__(256) void enc_mfma_kernel(
    const int* __restrict__ list, const int* __restrict__ countPtr,
    const u16* __restrict__ xb,
    const u16* __restrict__ w1f, const u16* __restrict__ w2f,
    const float* __restrict__ bia1, const float* __restrict__ bia2,
    float* __restrict__ h, u16* __restrict__ h16)
{
    __shared__ __align__(16) u16 hid[4][16 * 72];
    const int wv = threadIdx.x >> 6;
    const int lane = threadIdx.x & 63;
    const int tile = blockIdx.x * 4 + wv;
    const int count = *countPtr;
    if (tile * 16 >= count) return;
    const int quad = lane >> 4;
    const int mi = lane & 15;
    int idx = tile * 16 + mi;
    if (idx >= count) idx = count - 1;
    const int nid = list[idx];

    const short8 a0 = *(const short8*)(xb + (size_t)nid * H + quad * 8);
    const short8 a1 = *(const short8*)(xb + (size_t)nid * H + 32 + quad * 8);

    floatx4 acc[4];
#pragma unroll
    for (int t = 0; t < 4; ++t) acc[t] = (floatx4){0.f, 0.f, 0.f, 0.f};
#pragma unroll
    for (int t = 0; t < 4; ++t) {
        const short8 b0 = *(const short8*)(w1f + ((size_t)(0 * 4 + t) * 64 + lane) * 8);
        const short8 b1 = *(const short8*)(w1f + ((size_t)(1 * 4 + t) * 64 + lane) * 8);
        acc[t] = mfma16(a0, b0, acc[t]);
        acc[t] = mfma16(a1, b1, acc[t]);
    }

    u16* myh = hid[wv];
#pragma unroll
    for (int t = 0; t < 4; ++t) {
        const float bv = bia1[t * 16 + mi];
#pragma unroll
        for (int r = 0; r < 4; ++r) {
            const float v = fmaxf(acc[t][r] + bv, 0.0f);
            myh[(quad * 4 + r) * 72 + t * 16 + mi] = f2bf(v);
        }
    }
    asm volatile("s_waitcnt lgkmcnt(0)" ::: "memory");

    const short8 c0 = *(const short8*)(myh + mi * 72 + quad * 8);
    const short8 c1 = *(const short8*)(myh + mi * 72 + 32 + quad * 8);

    floatx4 acc2[4];
#pragma unroll
    for (int t = 0; t < 4; ++t) acc2[t] = (floatx4){0.f, 0.f, 0.f, 0.f};
#pragma unroll
    for (int t = 0; t < 4; ++t) {
        const short8 b0 = *(const short8*)(w2f + ((size_t)(0 * 4 + t) * 64 + lane) * 8);
        const short8 b1 = *(const short8*)(w2f + ((size_t)(1 * 4 + t) * 64 + lane) * 8);
        acc2[t] = mfma16(c0, b0, acc2[t]);
        acc2[t] = mfma16(c1, b1, acc2[t]);
    }

#pragma unroll
    for (int t = 0; t < 4; ++t) {
        const float bv = bia2[t * 16 + mi];
#pragma unroll
        for (int r = 0; r < 4; ++r) {
            const int row = quad * 4 + r;
            const int nr = __shfl(nid, row, 64);
            if (tile * 16 + row < count) {
                const float v = fmaxf(acc2[t][r] + bv, 0.0f);   // encoder outer relu
                h[(size_t)nr * H + t * 16 + mi] = v;
                h16[(size_t)nr * H + t * 16 + mi] = f2bf(v);
            }
        }
    }
}

// ---- MFMA MLP over consecutive nodes, in place (conv nn), no outer relu ----
__global__ __launch_bounds__(256) void mlp_mfma_kernel(
    const u16* __restrict__ w1f, const u16* __restrict__ w2f,
    const float* __restrict__ bia1, const float* __restrict__ bia2,
    float* __restrict__ h)
{
    __shared__ __align__(16) u16 hid[4][16 * 72];
    const int wv = threadIdx.x >> 6;
    const int lane = threadIdx.x & 63;
    const int tile = blockIdx.x * 4 + wv;
    if (tile >= NTILE) return;
    const int quad = lane >> 4;
    const int mi = lane & 15;
    const int row = tile * 16 + mi;
    const float* zr = h + (size_t)row * H;

    const float4 f0 = *(const float4*)(zr + quad * 8);
    const float4 f1 = *(const float4*)(zr + quad * 8 + 4);
    const float4 f2 = *(const float4*)(zr + 32 + quad * 8);
    const float4 f3 = *(const float4*)(zr + 32 + quad * 8 + 4);
    const short8 a0 = pack_bf8(f0, f1);
    const short8 a1 = pack_bf8(f2, f3);

    floatx4 acc[4];
#pragma unroll
    for (int t = 0; t < 4; ++t) acc[t] = (floatx4){0.f, 0.f, 0.f, 0.f};
#pragma unroll
    for (int t = 0; t < 4; ++t) {
        const short8 b0 = *(const short8*)(w1f + ((size_t)(0 * 4 + t) * 64 + lane) * 8);
        const short8 b1 = *(const short8*)(w1f + ((size_t)(1 * 4 + t) * 64 + lane) * 8);
        acc[t] = mfma16(a0, b0, acc[t]);
        acc[t] = mfma16(a1, b1, acc[t]);
    }

    u16* myh = hid[wv];
#pragma unroll
    for (int t = 0; t < 4; ++t) {
        const float bv = bia1[t * 16 + mi];
#pragma unroll
        for (int r = 0; r < 4; ++r) {
            const float v = fmaxf(acc[t][r] + bv, 0.0f);
            myh[(quad * 4 + r) * 72 + t * 16 + mi] = f2bf(v);
        }
    }
    asm volatile("s_waitcnt lgkmcnt(0)" ::: "memory");

    const short8 c0 = *(const short8*)(myh + mi * 72 + quad * 8);
    const short8 c1 = *(const short8*)(myh + mi * 72 + 32 + quad * 8);

    floatx4 acc2[4];
#pragma unroll
    for (int t = 0; t < 4; ++t) acc2[t] = (floatx4){0.f, 0.f, 0.f, 0.f};
#pragma unroll
    for (int t = 0; t < 4; ++t) {
        const short8 b0 = *(const short8*)(w2f + ((size_t)(0 * 4 + t) * 64 + lane) * 8);
        const short8 b1 = *(const short8*)(w2f + ((size_t)(1 * 4 + t) * 64 + lane) * 8);
        acc2[t] = mfma16(c0, b0, acc2[t]);
        acc2[t] = mfma16(c1, b1, acc2[t]);
    }

#pragma unroll
    for (int t = 0; t < 4; ++t) {
        const float bv = bia2[t * 16 + mi];
#pragma unroll
        for (int r = 0; r < 4; ++r) {
            const int orow = tile * 16 + quad * 4 + r;
            h[(size_t)orow * H + t * 16 + mi] = acc2[t][r] + bv;   // no relu
        }
    }
}

// ---------------- per-graph node ranges (batch is sorted) -------------------
__global__ void bounds_kernel(const int* __restrict__ batch, int* __restrict__ start)
{
    int g = blockIdx.x * blockDim.x + threadIdx.x;
    if (g > GNUM) return;
    int lo = 0, hi = NN;
    while (lo < hi) {
        int mid = (lo + hi) >> 1;
        if (batch[mid] < g) lo = mid + 1; else hi = mid;
    }
    start[g] = lo;
}

// ---- bucket+degree histogram: deg[dst]++ (global) + bucket counts ----------
__global__ __launch_bounds__(256) void bhist_kernel(
    const int* __restrict__ ei, int* __restrict__ deg, int* __restrict__ gbcount)
{
    __shared__ int cnt[NB];
    const int t = threadIdx.x;
    if (t < NB) cnt[t] = 0;
    __syncthreads();
    const int base = blockIdx.x * EPB;
#pragma unroll
    for (int v = 0; v < VPT; ++v) {
        const int e = base + v * 256 + t;
        if (e < NE) {
            const int d = ei[NE + e];
            atomicAdd(&deg[d], 1);
            atomicAdd(&cnt[d >> 10], 1);
        }
    }
    __syncthreads();
    if (t < NB && cnt[t]) atomicAdd(&gbcount[t], cnt[t]);
}

// ---- exclusive scan of the 128 bucket counts -> gcur -----------------------
__global__ __launch_bounds__(NB) void bscan_kernel(
    const int* __restrict__ gbcount, int* __restrict__ gcur)
{
    __shared__ int s[NB];
    const int t = threadIdx.x;
    const int v = gbcount[t];
    s[t] = v;
    __syncthreads();
#pragma unroll
    for (int off = 1; off < NB; off <<= 1) {
        int tmp = (t >= off) ? s[t - off] : 0;
        __syncthreads();
        s[t] += tmp;
        __syncthreads();
    }
    gcur[t] = s[t] - v;
}

// ---------------- node-degree scans (row_start, cursor) ---------------------
__global__ __launch_bounds__(256) void scan_a_kernel(
    const int* __restrict__ deg, int* __restrict__ row_start, int* __restrict__ bsum)
{
    __shared__ int s[256];
    const int t = threadIdx.x;
    const int idx = blockIdx.x * 256 + t;
    int v = (idx < NN) ? deg[idx] : 0;
    s[t] = v;
    __syncthreads();
#pragma unroll
    for (int off = 1; off < 256; off <<= 1) {
        int tmp = (t >= off) ? s[t - off] : 0;
        __syncthreads();
        s[t] += tmp;
        __syncthreads();
    }
    if (idx < NN) row_start[idx] = s[t] - v;  // exclusive
    if (t == 255) bsum[blockIdx.x] = s[255];
}

__global__ __launch_bounds__(512) void scan_b_kernel(int* __restrict__ bsum)
{
    __shared__ int s[512];
    const int t = threadIdx.x;
    int v = (t < NBLK_SCAN) ? bsum[t] : 0;
    s[t] = v;
    __syncthreads();
#pragma unroll
    for (int off = 1; off < 512; off <<= 1) {
        int tmp = (t >= off) ? s[t - off] : 0;
        __syncthreads();
        s[t] += tmp;
        __syncthreads();
    }
    if (t < NBLK_SCAN) bsum[t] = s[t] - v;  // exclusive
}

__global__ __launch_bounds__(256) void scan_c_kernel(
    int* __restrict__ row_start, const int* __restrict__ bsum, int* __restrict__ cursor)
{
    const int idx = blockIdx.x * 256 + threadIdx.x;
    if (idx < NN) {
        int rs = row_start[idx] + bsum[blockIdx.x];
        row_start[idx] = rs;
        cursor[idx] = rs;
    } else if (idx == NN) {
        row_start[NN] = NE;
    }
}

// ---- phase 1: LDS-ranked bucket partition, coalesced run writes ------------
__global__ __launch_bounds__(256) void p1_kernel(
    const int* __restrict__ ei, const float* __restrict__ ea,
    int* __restrict__ gcur,
    int2* __restrict__ tmp_sd, uint4* __restrict__ tmp_eab)
{
    __shared__ int cnt[NB];
    __shared__ int cur[NB];
    const int t = threadIdx.x;
    if (t < NB) cnt[t] = 0;
    __syncthreads();
    const int base = blockIdx.x * EPB;
    int dstv[VPT];
#pragma unroll
    for (int v = 0; v < VPT; ++v) {
        const int e = base + v * 256 + t;
        dstv[v] = -1;
        if (e < NE) {
            dstv[v] = ei[NE + e];
            atomicAdd(&cnt[dstv[v] >> 10], 1);
        }
    }
    __syncthreads();
    if (t < NB) cur[t] = cnt[t] ? atomicAdd(&gcur[t], cnt[t]) : 0;
    __syncthreads();
#pragma unroll
    for (int v = 0; v < VPT; ++v) {
        const int e = base + v * 256 + t;
        if (e < NE) {
            const int b = dstv[v] >> 10;
            const int pos = atomicAdd(&cur[b], 1);
            tmp_sd[pos] = make_int2(ei[e], dstv[v]);
            const float4* e4 = (const float4*)(ea + (size_t)e * EDIM);
            float4 a = e4[0], bb = e4[1];
            uint4 u;
            u.x = (u32)f2bf(a.x) | ((u32)f2bf(a.y) << 16);
            u.y = (u32)f2bf(a.z) | ((u32)f2bf(a.w) << 16);
            u.z = (u32)f2bf(bb.x) | ((u32)f2bf(bb.y) << 16);
            u.w = (u32)f2bf(bb.z) | ((u32)f2bf(bb.w) << 16);
            tmp_eab[pos] = u;
        }
    }
}

// ---- phase 2: in-bucket scatter to final CSR position ----------------------
__global__ __launch_bounds__(256) void p2_kernel(
    const int2* __restrict__ tmp_sd, const uint4* __restrict__ tmp_eab,
    int* __restrict__ cursor,
    int2* __restrict__ perm2, uint4* __restrict__ eab)
{
    const int base = blockIdx.x * EPB;
    const int t = threadIdx.x;
#pragma unroll
    for (int v = 0; v < VPT; ++v) {
        const int i = base + v * 256 + t;
        if (i < NE) {
            const int2 sd = tmp_sd[i];
            const int pos = atomicAdd(&cursor[sd.y], 1);
            perm2[pos] = sd;
            eab[pos] = tmp_eab[i];
        }
    }
}

// ---- edge-centric aggregation: one wave per 16 consecutive CSR edges -------
__global__ __launch_bounds__(256) void aggr_kernel(
    const int2* __restrict__ perm2,
    const u32* __restrict__ eab32,
    const float* __restrict__ We, const float* __restrict__ be,
    const u16* __restrict__ h16, float* __restrict__ h)
{
    const int lane = threadIdx.x & 63;
    const int chunk = blockIdx.x * 4 + (threadIdx.x >> 6);
    const int base = chunk * EPW;

    float we_r[EDIM];
#pragma unroll
    for (int d = 0; d < EDIM; ++d) we_r[d] = We[d * H + lane];
    const float be_r = be[lane];

    const int2 pd = perm2[base + (lane & 15)];
    const u32 eu = eab32[(size_t)base * 4 + lane];

    float hv[EPW];
#pragma unroll
    for (int j = 0; j < EPW; ++j) {
        const int sj = __builtin_amdgcn_readlane(pd.x, j);
        hv[j] = bf2f(h16[(size_t)sj * H + lane]);
    }

    float acc = 0.0f;
    int cur = __builtin_amdgcn_readlane(pd.y, 0);
#pragma unroll
    for (int j = 0; j < EPW; ++j) {
        const int dj = __builtin_amdgcn_readlane(pd.y, j);
        float msg = be_r;
#pragma unroll
        for (int p = 0; p < 4; ++p) {
            const u32 w2 = __builtin_amdgcn_readlane(eu, j * 4 + p);
            msg = fmaf(__uint_as_float(w2 << 16), we_r[2 * p], msg);
            msg = fmaf(__uint_as_float(w2 & 0xffff0000u), we_r[2 * p + 1], msg);
        }
        if (dj != cur) {                       // wave-uniform branch
            unsafeAtomicAdd(&h[(size_t)cur * H + lane], acc);
            acc = 0.0f;
            cur = dj;
        }
        acc += fmaxf(hv[j] + msg, 0.0f);
    }
    unsafeAtomicAdd(&h[(size_t)cur * H + lane], acc);
}

// ------- GraphNorm + relu, in place; refresh h16; optional pool accum -------
__global__ __launch_bounds__(1024) void graphnorm_kernel(
    float* __restrict__ h, u16* __restrict__ h16,
    const int* __restrict__ start,
    const float* __restrict__ w, const float* __restrict__ b,
    const float* __restrict__ a,
    float* __restrict__ pool, int do_pool)
{
    __shared__ float red1[16][H], red2[16][H];
    __shared__ float amean_s[H], rstd_s[H];
    const int g = blockIdx.x;
    const int lane = threadIdx.x & 63;
    const int wv = threadIdx.x >> 6;
    const int s = start[g], e = start[g + 1];

    float s1 = 0.f, s2 = 0.f;
    for (int i = s + wv; i < e; i += 16) {
        float v = h[(size_t)i * H + lane];
        s1 += v; s2 += v * v;
    }
    red1[wv][lane] = s1; red2[wv][lane] = s2;
    __syncthreads();
    if (threadIdx.x < H) {
        float t1 = 0.f, t2 = 0.f;
#pragma unroll
        for (int k = 0; k < 16; ++k) { t1 += red1[k][lane]; t2 += red2[k][lane]; }
        float cnt = fmaxf((float)(e - s), 1.0f);
        float mean = t1 / cnt;
        float alpha = a[lane];
        float var = t2 / cnt - (2.0f * alpha - alpha * alpha) * mean * mean;
        var = fmaxf(var, 0.0f);
        amean_s[lane] = alpha * mean;
        rstd_s[lane] = rsqrtf(var + EPSV);
    }
    __syncthreads();
    const float am = amean_s[lane], rstd = rstd_s[lane];
    const float ww = w[lane], bb = b[lane];
    float ps = 0.f;
    for (int i = s + wv; i < e; i += 16) {
        float v = (h[(size_t)i * H + lane] - am) * rstd * ww + bb;
        v = fmaxf(v, 0.0f);
        h[(size_t)i * H + lane] = v;
        h16[(size_t)i * H + lane] = f2bf(v);
        ps += v;
    }
    if (do_pool && e > s) unsafeAtomicAdd(&pool[g * H + lane], ps);
}

// ---------------- readout from pooled sums ----------------------------------
__global__ __launch_bounds__(64) void final_kernel(
    const float* __restrict__ pool,
    const float* __restrict__ W1, const float* __restrict__ b1,
    const float* __restrict__ W2, const float* __restrict__ b2,
    float* __restrict__ out)
{
    const int g = blockIdx.x;
    const int lane = threadIdx.x;
    const float gv = pool[g * H + lane];
    float acc = b1[lane];
#pragma unroll
    for (int d = 0; d < H; ++d)
        acc = fmaf(__shfl(gv, d, 64), W1[d * H + lane], acc);
    float r = fmaxf(acc, 0.0f);
    float v = r * W2[lane];
#pragma unroll
    for (int o = 32; o > 0; o >>= 1) v += __shfl_xor(v, o, 64);
    if (lane == 0) out[g] = v + b2[0];
}

extern "C" void kernel_launch(void* const* d_in, const int* in_sizes, int n_in,
                              void* d_out, int out_size, void* d_ws, size_t ws_size,
                              hipStream_t stream)
{
    const float* x      = (const float*)d_in[0];
    const int*   ei     = (const int*)  d_in[1];
    const float* ea     = (const float*)d_in[2];
    const int*   batch  = (const int*)  d_in[3];
    const float* ligW1  = (const float*)d_in[4];
    const float* ligb1  = (const float*)d_in[5];
    const float* ligW2  = (const float*)d_in[6];
    const float* ligb2  = (const float*)d_in[7];
    const float* protW1 = (const float*)d_in[8];
    const float* protb1 = (const float*)d_in[9];
    const float* protW2 = (const float*)d_in[10];
    const float* protb2 = (const float*)d_in[11];
    const float* convWe = (const float*)d_in[12];
    const float* convbe = (const float*)d_in[13];
    const float* convW1 = (const float*)d_in[14];
    const float* convb1 = (const float*)d_in[15];
    const float* convW2 = (const float*)d_in[16];
    const float* convb2 = (const float*)d_in[17];
    const float* normw  = (const float*)d_in[18];
    const float* normb  = (const float*)d_in[19];
    const float* norma  = (const float*)d_in[20];
    const float* outW1  = (const float*)d_in[21];
    const float* outb1  = (const float*)d_in[22];
    const float* outW2  = (const float*)d_in[23];
    const float* outb2  = (const float*)d_in[24];

    float* out = (float*)d_out;

    // -------- workspace layout (16B-aligned blocks first) -------------------
    float* h         = (float*)d_ws;                    // NN*H f32      25.6 MB
    uint4* eab       = (uint4*)(h + (size_t)NN * H);    // NE uint4      25.6 MB
    int2*  perm2     = (int2*)(eab + (size_t)NE);       // NE int2       12.8 MB
    u16*   h16       = (u16*)(perm2 + (size_t)NE);      // NN*H u16      12.8 MB
    u16*   xb        = h16 + (size_t)NN * H;            // NN*H u16      12.8 MB
    u16*   wf        = xb + (size_t)NN * H;             // 40960 u16     80 KB
    uint4* tmp_eab   = (uint4*)h;                       // NE uint4 (overlay h)
    int2*  tmp_sd    = (int2*)h16;                      // NE int2  (overlay h16)

    int*   deg       = (int*)(wf + 40960);              // NN   (zeroed)
    int*   ctr       = deg + NN;                        // 2    (zeroed)
    int*   gbcount   = ctr + 2;                         // NB   (zeroed)
    float* pool      = (float*)(gbcount + NB);          // GNUM*H (zeroed)
    int*   row_start = (int*)(pool + GNUM * H);         // NN+1
    int*   cursor    = row_start + (NN + 1);            // NN
    int*   gcur      = cursor + NN;                     // NB
    int*   bsum      = gcur + NB;                       // 512
    int*   start     = bsum + 512;                      // GNUM+1
    int*   lig_list  = start + (GNUM + 1);              // NN
    int*   prot_list = lig_list + NN;                   // NN

    hipMemsetAsync(deg, 0, ((size_t)NN + 2 + NB + GNUM * H) * sizeof(int), stream);

    // ---- independent prep (doesn't touch overlays) ----
    xb_kernel<<<(NN * H + 255) / 256, 256, 0, stream>>>(x, xb);
    prep_w_kernel<<<(10 * 4096 + 255) / 256, 256, 0, stream>>>(
        ligW1, ligW2, protW1, protW2, convW1, convW2, wf);
    partition_kernel<<<(NN + 255) / 256, 256, 0, stream>>>(x, ctr, lig_list, prot_list);
    bounds_kernel<<<2, 256, 0, stream>>>(batch, start);

    // ---- CSR build (2-phase bucketed fill; overlays h/h16) ----
    bhist_kernel<<<NBLK_E, 256, 0, stream>>>(ei, deg, gbcount);
    bscan_kernel<<<1, NB, 0, stream>>>(gbcount, gcur);
    scan_a_kernel<<<NBLK_SCAN, 256, 0, stream>>>(deg, row_start, bsum);
    scan_b_kernel<<<1, 512, 0, stream>>>(bsum);
    scan_c_kernel<<<NBLK_SCAN, 256, 0, stream>>>(row_start, bsum, cursor);
    p1_kernel<<<NBLK_E, 256, 0, stream>>>(ei, ea, gcur, tmp_sd, tmp_eab);
    p2_kernel<<<NBLK_E, 256, 0, stream>>>(tmp_sd, tmp_eab, cursor, perm2, eab);

    // ---- encoder (MFMA over lig/prot lists; after overlays are dead) ----
    const int enc_blocks = (NTILE + 3) / 4;   // worst case all nodes one type
    enc_mfma_kernel<<<enc_blocks, 256, 0, stream>>>(
        lig_list, &ctr[0], xb, wf + 0 * 4096, wf + 1 * 4096, ligb1, ligb2, h, h16);
    enc_mfma_kernel<<<enc_blocks, 256, 0, stream>>>(
        prot_list, &ctr[1], xb, wf + 2 * 4096, wf + 3 * 4096, protb1, protb2, h, h16);

    const int aggr_blocks = NE / EPW / 4;   // 25000, exact
    const int mlp_blocks = (NTILE + 3) / 4;
    for (int l = 0; l < 3; ++l) {
        aggr_kernel<<<aggr_blocks, 256, 0, stream>>>(
            perm2, (const u32*)eab,
            convWe + (size_t)l * EDIM * H, convbe + (size_t)l * H, h16, h);
        mlp_mfma_kernel<<<mlp_blocks, 256, 0, stream>>>(
            wf + (size_t)(4 + 2 * l) * 4096, wf + (size_t)(5 + 2 * l) * 4096,
            convb1 + (size_t)l * H, convb2 + (size_t)l * H, h);
        graphnorm_kernel<<<GNUM, 1024, 0, stream>>>(
            h, h16, start, normw + (size_t)l * H, normb + (size_t)l * H,
            norma + (size_t)l * H, pool, (l == 2) ? 1 : 0);
    }
    final_kernel<<<GNUM, 64, 0, stream>>>(pool, outW1, outb1, outW2, outb2, out);
}

// Round 10
// 617.628 us; speedup vs baseline: 1.5322x; 1.1555x over previous
//
#include <hip/hip_runtime.h>

#define NN 100000   // nodes
#define NE 1600000  // edges
#define IN_CH 41
#define EDIM 8
#define H 64
#define GNUM 256
#define ATOM 21
#define EPSV 1e-5f
#define EPW 16      // edges per wave in aggr (NE % EPW == 0)
#define NTILE (NN / 16)   // 6250 node tiles (exact)

#define BSH 9       // bucket shift: dst>>9, 512 dst per bucket
#define NBK 196     // ceil(NN / 512)
#define DPB 512     // dst per bucket
#define VPT 8       // edges per thread in bucket kernels
#define EPB (256 * VPT)                    // 2048 edges per block
#define NBLK_E ((NE + EPB - 1) / EPB)      // 782

typedef unsigned short u16;
typedef unsigned int u32;
typedef unsigned long long u64;
typedef __attribute__((ext_vector_type(8))) short short8;
typedef __attribute__((ext_vector_type(4))) float floatx4;

__device__ __forceinline__ u16 f2bf(float f) {
    u32 u = __float_as_uint(f);
    u32 r = (u + 0x7FFFu + ((u >> 16) & 1u)) >> 16;   // RNE
    return (u16)r;
}
__device__ __forceinline__ float bf2f(u16 u) {
    return __uint_as_float(((u32)u) << 16);
}
__device__ __forceinline__ floatx4 mfma16(short8 a, short8 b, floatx4 c) {
    return __builtin_amdgcn_mfma_f32_16x16x32_bf16(a, b, c, 0, 0, 0);
}
__device__ __forceinline__ short8 pack_bf8(float4 a, float4 b) {
    short8 s;
    s[0] = (short)f2bf(a.x); s[1] = (short)f2bf(a.y);
    s[2] = (short)f2bf(a.z); s[3] = (short)f2bf(a.w);
    s[4] = (short)f2bf(b.x); s[5] = (short)f2bf(b.y);
    s[6] = (short)f2bf(b.z); s[7] = (short)f2bf(b.w);
    return s;
}

// ---- partition: mask per node -> lig_list / prot_list ----------------------
__global__ __launch_bounds__(256) void partition_kernel(
    const float* __restrict__ x, int* __restrict__ ctr,   // ctr[0]=lig, ctr[1]=prot
    int* __restrict__ lig_list, int* __restrict__ prot_list)
{
    const int n = blockIdx.x * 256 + threadIdx.x;
    const int lane = threadIdx.x & 63;
    float m = 0.0f;
    if (n < NN) {
        const float* xr = x + (size_t)n * IN_CH + ATOM;
#pragma unroll
        for (int d = 0; d < IN_CH - ATOM; ++d) m += fabsf(xr[d]);
    }
    const bool valid = n < NN;
    const bool prot = valid && (m > 1e-6f);
    const bool lig = valid && !prot;

    const u64 bl = __ballot(lig);
    const u64 bp = __ballot(prot);
    const u64 below_m = (lane == 63) ? (~0ull >> 1) : ((1ull << lane) - 1ull);
    int base_l = 0, base_p = 0;
    if (lane == 0) {
        if (bl) base_l = atomicAdd(&ctr[0], (int)__popcll(bl));
        if (bp) base_p = atomicAdd(&ctr[1], (int)__popcll(bp));
    }
    base_l = __shfl(base_l, 0, 64);
    base_p = __shfl(base_p, 0, 64);
    if (lig)  lig_list [base_l + (int)__popcll(bl & below_m)] = n;
    if (prot) prot_list[base_p + (int)__popcll(bp & below_m)] = n;
}

// ---- xb: zero-padded bf16 copy of x [NN x 64] ------------------------------
__global__ __launch_bounds__(256) void xb_kernel(
    const float* __restrict__ x, u16* __restrict__ xb)
{
    const int id = blockIdx.x * 256 + threadIdx.x;
    if (id >= NN * H) return;
    const int n = id >> 6, d = id & 63;
    xb[id] = (d < IN_CH) ? f2bf(x[(size_t)n * IN_CH + d]) : (u16)0;
}

// ---- prep: swizzle 10 weight matrices into MFMA B-fragment order -----------
__global__ __launch_bounds__(256) void prep_w_kernel(
    const float* __restrict__ ligW1, const float* __restrict__ ligW2,
    const float* __restrict__ protW1, const float* __restrict__ protW2,
    const float* __restrict__ convW1, const float* __restrict__ convW2,
    u16* __restrict__ wf)
{
    const int id = blockIdx.x * 256 + threadIdx.x;
    if (id >= 10 * 4096) return;
    const int j = id & 7, l = (id >> 3) & 63, t = (id >> 9) & 3;
    const int c = (id >> 11) & 1, mat = id >> 12;
    const int k = c * 32 + ((l >> 4) * 8) + j;
    const int n = t * 16 + (l & 15);
    const float* src; int K = 64;
    if (mat == 0)      { src = ligW1;  K = IN_CH; }
    else if (mat == 1) { src = ligW2; }
    else if (mat == 2) { src = protW1; K = IN_CH; }
    else if (mat == 3) { src = protW2; }
    else {
        const int layer = (mat - 4) >> 1;
        src = (((mat - 4) & 1) ? convW2 : convW1) + (size_t)layer * H * H;
    }
    wf[id] = (k < K) ? f2bf(src[(size_t)k * H + n]) : (u16)0;
}

// ---- MFMA MLP over a gathered node list (encoder) --------------------------
__global__ __launch_bounds__(256) void enc_mfma_kernel(
    const int* __restrict__ list, const int* __restrict__ countPtr,
    const u16* __restrict__ xb,
    const u16* __restrict__ w1f, const u16* __restrict__ w2f,
    const float* __restrict__ bia1, const float* __restrict__ bia2,
    float* __restrict__ h, u16* __restrict__ h16)
{
    __shared__ __align__(16) u16 hid[4][16 * 72];
    const int wv = threadIdx.x >> 6;
    const int lane = threadIdx.x & 63;
    const int tile = blockIdx.x * 4 + wv;
    const int count = *countPtr;
    if (tile * 16 >= count) return;
    const int quad = lane >> 4;
    const int mi = lane & 15;
    int idx = tile * 16 + mi;
    if (idx >= count) idx = count - 1;
    const int nid = list[idx];

    const short8 a0 = *(const short8*)(xb + (size_t)nid * H + quad * 8);
    const short8 a1 = *(const short8*)(xb + (size_t)nid * H + 32 + quad * 8);

    floatx4 acc[4];
#pragma unroll
    for (int t = 0; t < 4; ++t) acc[t] = (floatx4){0.f, 0.f, 0.f, 0.f};
#pragma unroll
    for (int t = 0; t < 4; ++t) {
        const short8 b0 = *(const short8*)(w1f + ((size_t)(0 * 4 + t) * 64 + lane) * 8);
        const short8 b1 = *(const short8*)(w1f + ((size_t)(1 * 4 + t) * 64 + lane) * 8);
        acc[t] = mfma16(a0, b0, acc[t]);
        acc[t] = mfma16(a1, b1, acc[t]);
    }

    u16* myh = hid[wv];
#pragma unroll
    for (int t = 0; t < 4; ++t) {
        const float bv = bia1[t * 16 + mi];
#pragma unroll
        for (int r = 0; r < 4; ++r) {
            const float v = fmaxf(acc[t][r] + bv, 0.0f);
            myh[(quad * 4 + r) * 72 + t * 16 + mi] = f2bf(v);
        }
    }
    asm volatile("s_waitcnt lgkmcnt(0)" ::: "memory");

    const short8 c0 = *(const short8*)(myh + mi * 72 + quad * 8);
    const short8 c1 = *(const short8*)(myh + mi * 72 + 32 + quad * 8);

    floatx4 acc2[4];
#pragma unroll
    for (int t = 0; t < 4; ++t) acc2[t] = (floatx4){0.f, 0.f, 0.f, 0.f};
#pragma unroll
    for (int t = 0; t < 4; ++t) {
        const short8 b0 = *(const short8*)(w2f + ((size_t)(0 * 4 + t) * 64 + lane) * 8);
        const short8 b1 = *(const short8*)(w2f + ((size_t)(1 * 4 + t) * 64 + lane) * 8);
        acc2[t] = mfma16(c0, b0, acc2[t]);
        acc2[t] = mfma16(c1, b1, acc2[t]);
    }

#pragma unroll
    for (int t = 0; t < 4; ++t) {
        const float bv = bia2[t * 16 + mi];
#pragma unroll
        for (int r = 0; r < 4; ++r) {
            const int row = quad * 4 + r;
            const int nr = __shfl(nid, row, 64);
            if (tile * 16 + row < count) {
                const float v = fmaxf(acc2[t][r] + bv, 0.0f);   // encoder outer relu
                h[(size_t)nr * H + t * 16 + mi] = v;
                h16[(size_t)nr * H + t * 16 + mi] = f2bf(v);
            }
        }
    }
}

// ---- MFMA MLP over consecutive nodes, in place (conv nn), no outer relu ----
__global__ __launch_bounds__(256) void mlp_mfma_kernel(
    const u16* __restrict__ w1f, const u16* __restrict__ w2f,
    const float* __restrict__ bia1, const float* __restrict__ bia2,
    float* __restrict__ h)
{
    __shared__ __align__(16) u16 hid[4][16 * 72];
    const int wv = threadIdx.x >> 6;
    const int lane = threadIdx.x & 63;
    const int tile = blockIdx.x * 4 + wv;
    if (tile >= NTILE) return;
    const int quad = lane >> 4;
    const int mi = lane & 15;
    const int row = tile * 16 + mi;
    const float* zr = h + (size_t)row * H;

    const float4 f0 = *(const float4*)(zr + quad * 8);
    const float4 f1 = *(const float4*)(zr + quad * 8 + 4);
    const float4 f2 = *(const float4*)(zr + 32 + quad * 8);
    const float4 f3 = *(const float4*)(zr + 32 + quad * 8 + 4);
    const short8 a0 = pack_bf8(f0, f1);
    const short8 a1 = pack_bf8(f2, f3);

    floatx4 acc[4];
#pragma unroll
    for (int t = 0; t < 4; ++t) acc[t] = (floatx4){0.f, 0.f, 0.f, 0.f};
#pragma unroll
    for (int t = 0; t < 4; ++t) {
        const short8 b0 = *(const short8*)(w1f + ((size_t)(0 * 4 + t) * 64 + lane) * 8);
        const short8 b1 = *(const short8*)(w1f + ((size_t)(1 * 4 + t) * 64 + lane) * 8);
        acc[t] = mfma16(a0, b0, acc[t]);
        acc[t] = mfma16(a1, b1, acc[t]);
    }

    u16* myh = hid[wv];
#pragma unroll
    for (int t = 0; t < 4; ++t) {
        const float bv = bia1[t * 16 + mi];
#pragma unroll
        for (int r = 0; r < 4; ++r) {
            const float v = fmaxf(acc[t][r] + bv, 0.0f);
            myh[(quad * 4 + r) * 72 + t * 16 + mi] = f2bf(v);
        }
    }
    asm volatile("s_waitcnt lgkmcnt(0)" ::: "memory");

    const short8 c0 = *(const short8*)(myh + mi * 72 + quad * 8);
    const short8 c1 = *(const short8*)(myh + mi * 72 + 32 + quad * 8);

    floatx4 acc2[4];
#pragma unroll
    for (int t = 0; t < 4; ++t) acc2[t] = (floatx4){0.f, 0.f, 0.f, 0.f};
#pragma unroll
    for (int t = 0; t < 4; ++t) {
        const short8 b0 = *(const short8*)(w2f + ((size_t)(0 * 4 + t) * 64 + lane) * 8);
        const short8 b1 = *(const short8*)(w2f + ((size_t)(1 * 4 + t) * 64 + lane) * 8);
        acc2[t] = mfma16(c0, b0, acc2[t]);
        acc2[t] = mfma16(c1, b1, acc2[t]);
    }

#pragma unroll
    for (int t = 0; t < 4; ++t) {
        const float bv = bia2[t * 16 + mi];
#pragma unroll
        for (int r = 0; r < 4; ++r) {
            const int orow = tile * 16 + quad * 4 + r;
            h[(size_t)orow * H + t * 16 + mi] = acc2[t][r] + bv;   // no relu
        }
    }
}

// ---------------- per-graph node ranges (batch is sorted) -------------------
__global__ void bounds_kernel(const int* __restrict__ batch, int* __restrict__ start)
{
    int g = blockIdx.x * blockDim.x + threadIdx.x;
    if (g > GNUM) return;
    int lo = 0, hi = NN;
    while (lo < hi) {
        int mid = (lo + hi) >> 1;
        if (batch[mid] < g) lo = mid + 1; else hi = mid;
    }
    start[g] = lo;
}

// ---- bucket histogram (LDS only; no global per-node deg) -------------------
__global__ __launch_bounds__(256) void bhist_kernel(
    const int* __restrict__ ei, int* __restrict__ gbcount)
{
    __shared__ int cnt[NBK];
    const int t = threadIdx.x;
    if (t < NBK) cnt[t] = 0;
    __syncthreads();
    const int base = blockIdx.x * EPB;
#pragma unroll
    for (int v = 0; v < VPT; ++v) {
        const int e = base + v * 256 + t;
        if (e < NE) atomicAdd(&cnt[ei[NE + e] >> BSH], 1);
    }
    __syncthreads();
    if (t < NBK && cnt[t]) atomicAdd(&gbcount[t], cnt[t]);
}

// ---- exclusive scan of bucket counts -> gstart (and gcur working copy) -----
__global__ __launch_bounds__(256) void bscan_kernel(
    const int* __restrict__ gbcount, int* __restrict__ gstart, int* __restrict__ gcur)
{
    __shared__ int s[256];
    const int t = threadIdx.x;
    int v = (t < NBK) ? gbcount[t] : 0;
    s[t] = v;
    __syncthreads();
#pragma unroll
    for (int off = 1; off < 256; off <<= 1) {
        int tmp = (t >= off) ? s[t - off] : 0;
        __syncthreads();
        s[t] += tmp;
        __syncthreads();
    }
    if (t < NBK) { gstart[t] = s[t] - v; gcur[t] = s[t] - v; }
    if (t == 0) gstart[NBK] = NE;
}

// ---- phase 1: LDS-ranked bucket partition, coalesced run writes ------------
__global__ __launch_bounds__(256) void p1_kernel(
    const int* __restrict__ ei, const float* __restrict__ ea,
    int* __restrict__ gcur,
    int2* __restrict__ tmp_sd, uint4* __restrict__ tmp_eab)
{
    __shared__ int cnt[NBK];
    __shared__ int cur[NBK];
    const int t = threadIdx.x;
    if (t < NBK) cnt[t] = 0;
    __syncthreads();
    const int base = blockIdx.x * EPB;
    int dstv[VPT];
#pragma unroll
    for (int v = 0; v < VPT; ++v) {
        const int e = base + v * 256 + t;
        dstv[v] = -1;
        if (e < NE) {
            dstv[v] = ei[NE + e];
            atomicAdd(&cnt[dstv[v] >> BSH], 1);
        }
    }
    __syncthreads();
    if (t < NBK) cur[t] = cnt[t] ? atomicAdd(&gcur[t], cnt[t]) : 0;
    __syncthreads();
#pragma unroll
    for (int v = 0; v < VPT; ++v) {
        const int e = base + v * 256 + t;
        if (e < NE) {
            const int b = dstv[v] >> BSH;
            const int pos = atomicAdd(&cur[b], 1);
            tmp_sd[pos] = make_int2(ei[e], dstv[v]);
            const float4* e4 = (const float4*)(ea + (size_t)e * EDIM);
            float4 a = e4[0], bb = e4[1];
            uint4 u;
            u.x = (u32)f2bf(a.x) | ((u32)f2bf(a.y) << 16);
            u.y = (u32)f2bf(a.z) | ((u32)f2bf(a.w) << 16);
            u.z = (u32)f2bf(bb.x) | ((u32)f2bf(bb.y) << 16);
            u.w = (u32)f2bf(bb.z) | ((u32)f2bf(bb.w) << 16);
            tmp_eab[pos] = u;
        }
    }
}

// ---- per-bucket LDS counting sort -> exact dst-sorted CSR ------------------
__global__ __launch_bounds__(1024) void sort_kernel(
    const int2* __restrict__ tmp_sd, const uint4* __restrict__ tmp_eab,
    const int* __restrict__ gstart,
    int2* __restrict__ perm2, uint4* __restrict__ eab)
{
    __shared__ int hist[DPB];
    __shared__ int cursor[DPB];
    const int b = blockIdx.x;
    const int t = threadIdx.x;
    const int s = gstart[b], e = gstart[b + 1];
    const int dbase = b << BSH;

    if (t < DPB) hist[t] = 0;
    __syncthreads();
    for (int i = s + t; i < e; i += 1024)
        atomicAdd(&hist[tmp_sd[i].y - dbase], 1);
    __syncthreads();
    if (t < DPB) cursor[t] = hist[t];
    __syncthreads();
#pragma unroll
    for (int off = 1; off < DPB; off <<= 1) {
        int v = (t < DPB && t >= off) ? cursor[t - off] : 0;
        __syncthreads();
        if (t < DPB) cursor[t] += v;
        __syncthreads();
    }
    if (t < DPB) cursor[t] = s + cursor[t] - hist[t];   // exclusive + bucket base
    __syncthreads();
    for (int i = s + t; i < e; i += 1024) {
        const int2 sd = tmp_sd[i];
        const int pos = atomicAdd(&cursor[sd.y - dbase], 1);
        perm2[pos] = sd;
        eab[pos] = tmp_eab[i];
    }
}

// ---- edge-centric aggregation: one wave per 16 consecutive CSR edges -------
__global__ __launch_bounds__(256) void aggr_kernel(
    const int2* __restrict__ perm2,
    const u32* __restrict__ eab32,
    const float* __restrict__ We, const float* __restrict__ be,
    const u16* __restrict__ h16, float* __restrict__ h)
{
    const int lane = threadIdx.x & 63;
    const int chunk = blockIdx.x * 4 + (threadIdx.x >> 6);
    const int base = chunk * EPW;

    float we_r[EDIM];
#pragma unroll
    for (int d = 0; d < EDIM; ++d) we_r[d] = We[d * H + lane];
    const float be_r = be[lane];

    const int2 pd = perm2[base + (lane & 15)];
    const u32 eu = eab32[(size_t)base * 4 + lane];

    float hv[EPW];
#pragma unroll
    for (int j = 0; j < EPW; ++j) {
        const int sj = __builtin_amdgcn_readlane(pd.x, j);
        hv[j] = bf2f(h16[(size_t)sj * H + lane]);
    }

    float acc = 0.0f;
    int cur = __builtin_amdgcn_readlane(pd.y, 0);
#pragma unroll
    for (int j = 0; j < EPW; ++j) {
        const int dj = __builtin_amdgcn_readlane(pd.y, j);
        float msg = be_r;
#pragma unroll
        for (int p = 0; p < 4; ++p) {
            const u32 w2 = __builtin_amdgcn_readlane(eu, j * 4 + p);
            msg = fmaf(__uint_as_float(w2 << 16), we_r[2 * p], msg);
            msg = fmaf(__uint_as_float(w2 & 0xffff0000u), we_r[2 * p + 1], msg);
        }
        if (dj != cur) {                       // wave-uniform branch
            unsafeAtomicAdd(&h[(size_t)cur * H + lane], acc);
            acc = 0.0f;
            cur = dj;
        }
        acc += fmaxf(hv[j] + msg, 0.0f);
    }
    unsafeAtomicAdd(&h[(size_t)cur * H + lane], acc);
}

// ------- GraphNorm + relu, in place; refresh h16; optional pool accum -------
__global__ __launch_bounds__(1024) void graphnorm_kernel(
    float* __restrict__ h, u16* __restrict__ h16,
    const int* __restrict__ start,
    const float* __restrict__ w, const float* __restrict__ b,
    const float* __restrict__ a,
    float* __restrict__ pool, int do_pool)
{
    __shared__ float red1[16][H], red2[16][H];
    __shared__ float amean_s[H], rstd_s[H];
    const int g = blockIdx.x;
    const int lane = threadIdx.x & 63;
    const int wv = threadIdx.x >> 6;
    const int s = start[g], e = start[g + 1];

    float s1 = 0.f, s2 = 0.f;
    for (int i = s + wv; i < e; i += 16) {
        float v = h[(size_t)i * H + lane];
        s1 += v; s2 += v * v;
    }
    red1[wv][lane] = s1; red2[wv][lane] = s2;
    __syncthreads();
    if (threadIdx.x < H) {
        float t1 = 0.f, t2 = 0.f;
#pragma unroll
        for (int k = 0; k < 16; ++k) { t1 += red1[k][lane]; t2 += red2[k][lane]; }
        float cnt = fmaxf((float)(e - s), 1.0f);
        float mean = t1 / cnt;
        float alpha = a[lane];
        float var = t2 / cnt - (2.0f * alpha - alpha * alpha) * mean * mean;
        var = fmaxf(var, 0.0f);
        amean_s[lane] = alpha * mean;
        rstd_s[lane] = rsqrtf(var + EPSV);
    }
    __syncthreads();
    const float am = amean_s[lane], rstd = rstd_s[lane];
    const float ww = w[lane], bb = b[lane];
    float ps = 0.f;
    for (int i = s + wv; i < e; i += 16) {
        float v = (h[(size_t)i * H + lane] - am) * rstd * ww + bb;
        v = fmaxf(v, 0.0f);
        h[(size_t)i * H + lane] = v;
        h16[(size_t)i * H + lane] = f2bf(v);
        ps += v;
    }
    if (do_pool && e > s) unsafeAtomicAdd(&pool[g * H + lane], ps);
}

// ---------------- readout from pooled sums ----------------------------------
__global__ __launch_bounds__(64) void final_kernel(
    const float* __restrict__ pool,
    const float* __restrict__ W1, const float* __restrict__ b1,
    const float* __restrict__ W2, const float* __restrict__ b2,
    float* __restrict__ out)
{
    const int g = blockIdx.x;
    const int lane = threadIdx.x;
    const float gv = pool[g * H + lane];
    float acc = b1[lane];
#pragma unroll
    for (int d = 0; d < H; ++d)
        acc = fmaf(__shfl(gv, d, 64), W1[d * H + lane], acc);
    float r = fmaxf(acc, 0.0f);
    float v = r * W2[lane];
#pragma unroll
    for (int o = 32; o > 0; o >>= 1) v += __shfl_xor(v, o, 64);
    if (lane == 0) out[g] = v + b2[0];
}

extern "C" void kernel_launch(void* const* d_in, const int* in_sizes, int n_in,
                              void* d_out, int out_size, void* d_ws, size_t ws_size,
                              hipStream_t stream)
{
    const float* x      = (const float*)d_in[0];
    const int*   ei     = (const int*)  d_in[1];
    const float* ea     = (const float*)d_in[2];
    const int*   batch  = (const int*)  d_in[3];
    const float* ligW1  = (const float*)d_in[4];
    const float* ligb1  = (const float*)d_in[5];
    const float* ligW2  = (const float*)d_in[6];
    const float* ligb2  = (const float*)d_in[7];
    const float* protW1 = (const float*)d_in[8];
    const float* protb1 = (const float*)d_in[9];
    const float* protW2 = (const float*)d_in[10];
    const float* protb2 = (const float*)d_in[11];
    const float* convWe = (const float*)d_in[12];
    const float* convbe = (const float*)d_in[13];
    const float* convW1 = (const float*)d_in[14];
    const float* convb1 = (const float*)d_in[15];
    const float* convW2 = (const float*)d_in[16];
    const float* convb2 = (const float*)d_in[17];
    const float* normw  = (const float*)d_in[18];
    const float* normb  = (const float*)d_in[19];
    const float* norma  = (const float*)d_in[20];
    const float* outW1  = (const float*)d_in[21];
    const float* outb1  = (const float*)d_in[22];
    const float* outW2  = (const float*)d_in[23];
    const float* outb2  = (const float*)d_in[24];

    float* out = (float*)d_out;

    // -------- workspace layout (16B-aligned blocks first) -------------------
    float* h         = (float*)d_ws;                    // NN*H f32      25.6 MB
    uint4* eab       = (uint4*)(h + (size_t)NN * H);    // NE uint4      25.6 MB
    int2*  perm2     = (int2*)(eab + (size_t)NE);       // NE int2       12.8 MB
    u16*   h16       = (u16*)(perm2 + (size_t)NE);      // NN*H u16      12.8 MB
    u16*   xb        = h16 + (size_t)NN * H;            // NN*H u16      12.8 MB
    u16*   wf        = xb + (size_t)NN * H;             // 40960 u16     80 KB
    uint4* tmp_eab   = (uint4*)h;                       // NE uint4 (overlay h)
    int2*  tmp_sd    = (int2*)h16;                      // NE int2  (overlay h16)

    int*   ctr       = (int*)(wf + 40960);              // 2     (zeroed)
    int*   gbcount   = ctr + 2;                         // NBK   (zeroed)
    float* pool      = (float*)(gbcount + NBK);         // GNUM*H (zeroed)
    int*   gstart    = (int*)(pool + GNUM * H);         // NBK+1
    int*   gcur      = gstart + (NBK + 1);              // NBK
    int*   start     = gcur + NBK;                      // GNUM+1
    int*   lig_list  = start + (GNUM + 1);              // NN
    int*   prot_list = lig_list + NN;                   // NN

    hipMemsetAsync(ctr, 0, ((size_t)2 + NBK + GNUM * H) * sizeof(int), stream);

    // ---- independent prep (doesn't touch overlays) ----
    xb_kernel<<<(NN * H + 255) / 256, 256, 0, stream>>>(x, xb);
    prep_w_kernel<<<(10 * 4096 + 255) / 256, 256, 0, stream>>>(
        ligW1, ligW2, protW1, protW2, convW1, convW2, wf);
    partition_kernel<<<(NN + 255) / 256, 256, 0, stream>>>(x, ctr, lig_list, prot_list);
    bounds_kernel<<<2, 256, 0, stream>>>(batch, start);

    // ---- CSR build: bucket hist -> scan -> partition -> per-bucket sort ----
    bhist_kernel<<<NBLK_E, 256, 0, stream>>>(ei, gbcount);
    bscan_kernel<<<1, 256, 0, stream>>>(gbcount, gstart, gcur);
    p1_kernel<<<NBLK_E, 256, 0, stream>>>(ei, ea, gcur, tmp_sd, tmp_eab);
    sort_kernel<<<NBK, 1024, 0, stream>>>(tmp_sd, tmp_eab, gstart, perm2, eab);

    // ---- encoder (MFMA over lig/prot lists; after overlays are dead) ----
    const int enc_blocks = (NTILE + 3) / 4;
    enc_mfma_kernel<<<enc_blocks, 256, 0, stream>>>(
        lig_list, &ctr[0], xb, wf + 0 * 4096, wf + 1 * 4096, ligb1, ligb2, h, h16);
    enc_mfma_kernel<<<enc_blocks, 256, 0, stream>>>(
        prot_list, &ctr[1], xb, wf + 2 * 4096, wf + 3 * 4096, protb1, protb2, h, h16);

    const int aggr_blocks = NE / EPW / 4;   // 25000, exact
    const int mlp_blocks = (NTILE + 3) / 4;
    for (int l = 0; l < 3; ++l) {
        aggr_kernel<<<aggr_blocks, 256, 0, stream>>>(
            perm2, (const u32*)eab,
            convWe + (size_t)l * EDIM * H, convbe + (size_t)l * H, h16, h);
        mlp_mfma_kernel<<<mlp_blocks, 256, 0, stream>>>(
            wf + (size_t)(4 + 2 * l) * 4096, wf + (size_t)(5 + 2 * l) * 4096,
            convb1 + (size_t)l * H, convb2 + (size_t)l * H, h);
        graphnorm_kernel<<<GNUM, 1024, 0, stream>>>(
            h, h16, start, normw + (size_t)l * H, normb + (size_t)l * H,
            norma + (size_t)l * H, pool, (l == 2) ? 1 : 0);
    }
    final_kernel<<<GNUM, 64, 0, stream>>>(pool, outW1, outb1, outW2, outb2, out);
}

// Round 11
// 614.630 us; speedup vs baseline: 1.5397x; 1.0049x over previous
//
#include <hip/hip_runtime.h>

#define NN 100000   // nodes
#define NE 1600000  // edges
#define IN_CH 41
#define EDIM 8
#define H 64
#define GNUM 256
#define ATOM 21
#define EPSV 1e-5f
#define EPW 16      // edges per wave in aggr (NE % EPW == 0)
#define NTILE (NN / 16)   // 6250 node tiles (exact)

#define BSH 9       // bucket shift: dst>>9, 512 dst per bucket
#define NBK 196     // ceil(NN / 512)
#define DPB 512     // dst per bucket
#define VPT 8       // edges per thread in bucket kernels
#define EPB (256 * VPT)                    // 2048 edges per block (bhist)
#define NBLK_E ((NE + EPB - 1) / EPB)      // 782
#define EPB_P1 (1024 * VPT)                // 8192 edges per block (p1)
#define NBLK_P1 ((NE + EPB_P1 - 1) / EPB_P1)  // 196

typedef unsigned short u16;
typedef unsigned int u32;
typedef unsigned long long u64;
typedef __attribute__((ext_vector_type(8))) short short8;
typedef __attribute__((ext_vector_type(4))) float floatx4;

__device__ __forceinline__ u16 f2bf(float f) {
    u32 u = __float_as_uint(f);
    u32 r = (u + 0x7FFFu + ((u >> 16) & 1u)) >> 16;   // RNE
    return (u16)r;
}
__device__ __forceinline__ float bf2f(u16 u) {
    return __uint_as_float(((u32)u) << 16);
}
__device__ __forceinline__ floatx4 mfma16(short8 a, short8 b, floatx4 c) {
    return __builtin_amdgcn_mfma_f32_16x16x32_bf16(a, b, c, 0, 0, 0);
}
__device__ __forceinline__ short8 pack_bf8(float4 a, float4 b) {
    short8 s;
    s[0] = (short)f2bf(a.x); s[1] = (short)f2bf(a.y);
    s[2] = (short)f2bf(a.z); s[3] = (short)f2bf(a.w);
    s[4] = (short)f2bf(b.x); s[5] = (short)f2bf(b.y);
    s[6] = (short)f2bf(b.z); s[7] = (short)f2bf(b.w);
    return s;
}

// ---- partition: mask per node -> lig_list / prot_list ----------------------
__global__ __launch_bounds__(256) void partition_kernel(
    const float* __restrict__ x, int* __restrict__ ctr,   // ctr[0]=lig, ctr[1]=prot
    int* __restrict__ lig_list, int* __restrict__ prot_list)
{
    const int n = blockIdx.x * 256 + threadIdx.x;
    const int lane = threadIdx.x & 63;
    float m = 0.0f;
    if (n < NN) {
        const float* xr = x + (size_t)n * IN_CH + ATOM;
#pragma unroll
        for (int d = 0; d < IN_CH - ATOM; ++d) m += fabsf(xr[d]);
    }
    const bool valid = n < NN;
    const bool prot = valid && (m > 1e-6f);
    const bool lig = valid && !prot;

    const u64 bl = __ballot(lig);
    const u64 bp = __ballot(prot);
    const u64 below_m = (lane == 63) ? (~0ull >> 1) : ((1ull << lane) - 1ull);
    int base_l = 0, base_p = 0;
    if (lane == 0) {
        if (bl) base_l = atomicAdd(&ctr[0], (int)__popcll(bl));
        if (bp) base_p = atomicAdd(&ctr[1], (int)__popcll(bp));
    }
    base_l = __shfl(base_l, 0, 64);
    base_p = __shfl(base_p, 0, 64);
    if (lig)  lig_list [base_l + (int)__popcll(bl & below_m)] = n;
    if (prot) prot_list[base_p + (int)__popcll(bp & below_m)] = n;
}

// ---- xb: zero-padded bf16 copy of x [NN x 64] ------------------------------
__global__ __launch_bounds__(256) void xb_kernel(
    const float* __restrict__ x, u16* __restrict__ xb)
{
    const int id = blockIdx.x * 256 + threadIdx.x;
    if (id >= NN * H) return;
    const int n = id >> 6, d = id & 63;
    xb[id] = (d < IN_CH) ? f2bf(x[(size_t)n * IN_CH + d]) : (u16)0;
}

// ---- prep: swizzle 10 weight matrices into MFMA B-fragment order -----------
__global__ __launch_bounds__(256) void prep_w_kernel(
    const float* __restrict__ ligW1, const float* __restrict__ ligW2,
    const float* __restrict__ protW1, const float* __restrict__ protW2,
    const float* __restrict__ convW1, const float* __restrict__ convW2,
    u16* __restrict__ wf)
{
    const int id = blockIdx.x * 256 + threadIdx.x;
    if (id >= 10 * 4096) return;
    const int j = id & 7, l = (id >> 3) & 63, t = (id >> 9) & 3;
    const int c = (id >> 11) & 1, mat = id >> 12;
    const int k = c * 32 + ((l >> 4) * 8) + j;
    const int n = t * 16 + (l & 15);
    const float* src; int K = 64;
    if (mat == 0)      { src = ligW1;  K = IN_CH; }
    else if (mat == 1) { src = ligW2; }
    else if (mat == 2) { src = protW1; K = IN_CH; }
    else if (mat == 3) { src = protW2; }
    else {
        const int layer = (mat - 4) >> 1;
        src = (((mat - 4) & 1) ? convW2 : convW1) + (size_t)layer * H * H;
    }
    wf[id] = (k < K) ? f2bf(src[(size_t)k * H + n]) : (u16)0;
}

// ---- MFMA MLP over a gathered node list (encoder) --------------------------
__global__ __launch_bounds__(256) void enc_mfma_kernel(
    const int* __restrict__ list, const int* __restrict__ countPtr,
    const u16* __restrict__ xb,
    const u16* __restrict__ w1f, const u16* __restrict__ w2f,
    const float* __restrict__ bia1, const float* __restrict__ bia2,
    float* __restrict__ h, u16* __restrict__ h16)
{
    __shared__ __align__(16) u16 hid[4][16 * 72];
    const int wv = threadIdx.x >> 6;
    const int lane = threadIdx.x & 63;
    const int tile = blockIdx.x * 4 + wv;
    const int count = *countPtr;
    if (tile * 16 >= count) return;
    const int quad = lane >> 4;
    const int mi = lane & 15;
    int idx = tile * 16 + mi;
    if (idx >= count) idx = count - 1;
    const int nid = list[idx];

    const short8 a0 = *(const short8*)(xb + (size_t)nid * H + quad * 8);
    const short8 a1 = *(const short8*)(xb + (size_t)nid * H + 32 + quad * 8);

    floatx4 acc[4];
#pragma unroll
    for (int t = 0; t < 4; ++t) acc[t] = (floatx4){0.f, 0.f, 0.f, 0.f};
#pragma unroll
    for (int t = 0; t < 4; ++t) {
        const short8 b0 = *(const short8*)(w1f + ((size_t)(0 * 4 + t) * 64 + lane) * 8);
        const short8 b1 = *(const short8*)(w1f + ((size_t)(1 * 4 + t) * 64 + lane) * 8);
        acc[t] = mfma16(a0, b0, acc[t]);
        acc[t] = mfma16(a1, b1, acc[t]);
    }

    u16* myh = hid[wv];
#pragma unroll
    for (int t = 0; t < 4; ++t) {
        const float bv = bia1[t * 16 + mi];
#pragma unroll
        for (int r = 0; r < 4; ++r) {
            const float v = fmaxf(acc[t][r] + bv, 0.0f);
            myh[(quad * 4 + r) * 72 + t * 16 + mi] = f2bf(v);
        }
    }
    asm volatile("s_waitcnt lgkmcnt(0)" ::: "memory");

    const short8 c0 = *(const short8*)(myh + mi * 72 + quad * 8);
    const short8 c1 = *(const short8*)(myh + mi * 72 + 32 + quad * 8);

    floatx4 acc2[4];
#pragma unroll
    for (int t = 0; t < 4; ++t) acc2[t] = (floatx4){0.f, 0.f, 0.f, 0.f};
#pragma unroll
    for (int t = 0; t < 4; ++t) {
        const short8 b0 = *(const short8*)(w2f + ((size_t)(0 * 4 + t) * 64 + lane) * 8);
        const short8 b1 = *(const short8*)(w2f + ((size_t)(1 * 4 + t) * 64 + lane) * 8);
        acc2[t] = mfma16(c0, b0, acc2[t]);
        acc2[t] = mfma16(c1, b1, acc2[t]);
    }

#pragma unroll
    for (int t = 0; t < 4; ++t) {
        const float bv = bia2[t * 16 + mi];
#pragma unroll
        for (int r = 0; r < 4; ++r) {
            const int row = quad * 4 + r;
            const int nr = __shfl(nid, row, 64);
            if (tile * 16 + row < count) {
                const float v = fmaxf(acc2[t][r] + bv, 0.0f);   // encoder outer relu
                h[(size_t)nr * H + t * 16 + mi] = v;
                h16[(size_t)nr * H + t * 16 + mi] = f2bf(v);
            }
        }
    }
}

// ---- MFMA MLP over consecutive nodes, in place (conv nn), no outer relu ----
__global__ __launch_bounds__(256) void mlp_mfma_kernel(
    const u16* __restrict__ w1f, const u16* __restrict__ w2f,
    const float* __restrict__ bia1, const float* __restrict__ bia2,
    float* __restrict__ h)
{
    __shared__ __align__(16) u16 hid[4][16 * 72];
    const int wv = threadIdx.x >> 6;
    const int lane = threadIdx.x & 63;
    const int tile = blockIdx.x * 4 + wv;
    if (tile >= NTILE) return;
    const int quad = lane >> 4;
    const int mi = lane & 15;
    const int row = tile * 16 + mi;
    const float* zr = h + (size_t)row * H;

    const float4 f0 = *(const float4*)(zr + quad * 8);
    const float4 f1 = *(const float4*)(zr + quad * 8 + 4);
    const float4 f2 = *(const float4*)(zr + 32 + quad * 8);
    const float4 f3 = *(const float4*)(zr + 32 + quad * 8 + 4);
    const short8 a0 = pack_bf8(f0, f1);
    const short8 a1 = pack_bf8(f2, f3);

    floatx4 acc[4];
#pragma unroll
    for (int t = 0; t < 4; ++t) acc[t] = (floatx4){0.f, 0.f, 0.f, 0.f};
#pragma unroll
    for (int t = 0; t < 4; ++t) {
        const short8 b0 = *(const short8*)(w1f + ((size_t)(0 * 4 + t) * 64 + lane) * 8);
        const short8 b1 = *(const short8*)(w1f + ((size_t)(1 * 4 + t) * 64 + lane) * 8);
        acc[t] = mfma16(a0, b0, acc[t]);
        acc[t] = mfma16(a1, b1, acc[t]);
    }

    u16* myh = hid[wv];
#pragma unroll
    for (int t = 0; t < 4; ++t) {
        const float bv = bia1[t * 16 + mi];
#pragma unroll
        for (int r = 0; r < 4; ++r) {
            const float v = fmaxf(acc[t][r] + bv, 0.0f);
            myh[(quad * 4 + r) * 72 + t * 16 + mi] = f2bf(v);
        }
    }
    asm volatile("s_waitcnt lgkmcnt(0)" ::: "memory");

    const short8 c0 = *(const short8*)(myh + mi * 72 + quad * 8);
    const short8 c1 = *(const short8*)(myh + mi * 72 + 32 + quad * 8);

    floatx4 acc2[4];
#pragma unroll
    for (int t = 0; t < 4; ++t) acc2[t] = (floatx4){0.f, 0.f, 0.f, 0.f};
#pragma unroll
    for (int t = 0; t < 4; ++t) {
        const short8 b0 = *(const short8*)(w2f + ((size_t)(0 * 4 + t) * 64 + lane) * 8);
        const short8 b1 = *(const short8*)(w2f + ((size_t)(1 * 4 + t) * 64 + lane) * 8);
        acc2[t] = mfma16(c0, b0, acc2[t]);
        acc2[t] = mfma16(c1, b1, acc2[t]);
    }

#pragma unroll
    for (int t = 0; t < 4; ++t) {
        const float bv = bia2[t * 16 + mi];
#pragma unroll
        for (int r = 0; r < 4; ++r) {
            const int orow = tile * 16 + quad * 4 + r;
            h[(size_t)orow * H + t * 16 + mi] = acc2[t][r] + bv;   // no relu
        }
    }
}

// ---------------- per-graph node ranges (batch is sorted) -------------------
__global__ void bounds_kernel(const int* __restrict__ batch, int* __restrict__ start)
{
    int g = blockIdx.x * blockDim.x + threadIdx.x;
    if (g > GNUM) return;
    int lo = 0, hi = NN;
    while (lo < hi) {
        int mid = (lo + hi) >> 1;
        if (batch[mid] < g) lo = mid + 1; else hi = mid;
    }
    start[g] = lo;
}

// ---- bucket histogram (LDS only) -------------------------------------------
__global__ __launch_bounds__(256) void bhist_kernel(
    const int* __restrict__ ei, int* __restrict__ gbcount)
{
    __shared__ int cnt[NBK];
    const int t = threadIdx.x;
    if (t < NBK) cnt[t] = 0;
    __syncthreads();
    const int base = blockIdx.x * EPB;
#pragma unroll
    for (int v = 0; v < VPT; ++v) {
        const int e = base + v * 256 + t;
        if (e < NE) atomicAdd(&cnt[ei[NE + e] >> BSH], 1);
    }
    __syncthreads();
    if (t < NBK && cnt[t]) atomicAdd(&gbcount[t], cnt[t]);
}

// ---- exclusive scan of bucket counts -> gstart (and gcur working copy) -----
__global__ __launch_bounds__(256) void bscan_kernel(
    const int* __restrict__ gbcount, int* __restrict__ gstart, int* __restrict__ gcur)
{
    __shared__ int s[256];
    const int t = threadIdx.x;
    int v = (t < NBK) ? gbcount[t] : 0;
    s[t] = v;
    __syncthreads();
#pragma unroll
    for (int off = 1; off < 256; off <<= 1) {
        int tmp = (t >= off) ? s[t - off] : 0;
        __syncthreads();
        s[t] += tmp;
        __syncthreads();
    }
    if (t < NBK) { gstart[t] = s[t] - v; gcur[t] = s[t] - v; }
    if (t == 0) gstart[NBK] = NE;
}

// ---- phase 1: bucket partition of (src,dst,eid) records, 16B stores --------
__global__ __launch_bounds__(1024) void p1_kernel(
    const int* __restrict__ ei,
    int* __restrict__ gcur,
    int4* __restrict__ tmp_sde)
{
    __shared__ int cnt[NBK];
    __shared__ int cur[NBK];
    const int t = threadIdx.x;
    if (t < NBK) cnt[t] = 0;
    __syncthreads();
    const int base = blockIdx.x * EPB_P1;
    int dstv[VPT];
#pragma unroll
    for (int v = 0; v < VPT; ++v) {
        const int e = base + v * 1024 + t;
        dstv[v] = -1;
        if (e < NE) {
            dstv[v] = ei[NE + e];
            atomicAdd(&cnt[dstv[v] >> BSH], 1);
        }
    }
    __syncthreads();
    if (t < NBK) cur[t] = cnt[t] ? atomicAdd(&gcur[t], cnt[t]) : 0;
    __syncthreads();
#pragma unroll
    for (int v = 0; v < VPT; ++v) {
        const int e = base + v * 1024 + t;
        if (e < NE) {
            const int b = dstv[v] >> BSH;
            const int pos = atomicAdd(&cur[b], 1);
            tmp_sde[pos] = make_int4(ei[e], dstv[v], e, 0);
        }
    }
}

// ---- per-bucket LDS counting sort + ea gather -> exact dst-sorted CSR ------
__global__ __launch_bounds__(1024) void sort_kernel(
    const int4* __restrict__ tmp_sde, const float* __restrict__ ea,
    const int* __restrict__ gstart,
    int2* __restrict__ perm2, uint4* __restrict__ eab)
{
    __shared__ int hist[DPB];
    __shared__ int cursor[DPB];
    const int b = blockIdx.x;
    const int t = threadIdx.x;
    const int s = gstart[b], e = gstart[b + 1];
    const int dbase = b << BSH;

    if (t < DPB) hist[t] = 0;
    __syncthreads();
    for (int i = s + t; i < e; i += 1024)
        atomicAdd(&hist[tmp_sde[i].y - dbase], 1);
    __syncthreads();
    if (t < DPB) cursor[t] = hist[t];
    __syncthreads();
#pragma unroll
    for (int off = 1; off < DPB; off <<= 1) {
        int v = (t < DPB && t >= off) ? cursor[t - off] : 0;
        __syncthreads();
        if (t < DPB) cursor[t] += v;
        __syncthreads();
    }
    if (t < DPB) cursor[t] = s + cursor[t] - hist[t];   // exclusive + bucket base
    __syncthreads();
    for (int i = s + t; i < e; i += 1024) {
        const int4 sde = tmp_sde[i];
        const float4* e4 = (const float4*)(ea + (size_t)sde.z * EDIM);
        const float4 a = e4[0], bb = e4[1];
        uint4 u;
        u.x = (u32)f2bf(a.x) | ((u32)f2bf(a.y) << 16);
        u.y = (u32)f2bf(a.z) | ((u32)f2bf(a.w) << 16);
        u.z = (u32)f2bf(bb.x) | ((u32)f2bf(bb.y) << 16);
        u.w = (u32)f2bf(bb.z) | ((u32)f2bf(bb.w) << 16);
        const int pos = atomicAdd(&cursor[sde.y - dbase], 1);
        perm2[pos] = make_int2(sde.x, sde.y);
        eab[pos] = u;
    }
}

// ---- edge-centric aggregation: one wave per 16 consecutive CSR edges -------
__global__ __launch_bounds__(256) void aggr_kernel(
    const int2* __restrict__ perm2,
    const u32* __restrict__ eab32,
    const float* __restrict__ We, const float* __restrict__ be,
    const u16* __restrict__ h16, float* __restrict__ h)
{
    const int lane = threadIdx.x & 63;
    const int chunk = blockIdx.x * 4 + (threadIdx.x >> 6);
    const int base = chunk * EPW;

    float we_r[EDIM];
#pragma unroll
    for (int d = 0; d < EDIM; ++d) we_r[d] = We[d * H + lane];
    const float be_r = be[lane];

    const int2 pd = perm2[base + (lane & 15)];
    const u32 eu = eab32[(size_t)base * 4 + lane];

    float hv[EPW];
#pragma unroll
    for (int j = 0; j < EPW; ++j) {
        const int sj = __builtin_amdgcn_readlane(pd.x, j);
        hv[j] = bf2f(h16[(size_t)sj * H + lane]);
    }

    float acc = 0.0f;
    int cur = __builtin_amdgcn_readlane(pd.y, 0);
#pragma unroll
    for (int j = 0; j < EPW; ++j) {
        const int dj = __builtin_amdgcn_readlane(pd.y, j);
        float msg = be_r;
#pragma unroll
        for (int p = 0; p < 4; ++p) {
            const u32 w2 = __builtin_amdgcn_readlane(eu, j * 4 + p);
            msg = fmaf(__uint_as_float(w2 << 16), we_r[2 * p], msg);
            msg = fmaf(__uint_as_float(w2 & 0xffff0000u), we_r[2 * p + 1], msg);
        }
        if (dj != cur) {                       // wave-uniform branch
            unsafeAtomicAdd(&h[(size_t)cur * H + lane], acc);
            acc = 0.0f;
            cur = dj;
        }
        acc += fmaxf(hv[j] + msg, 0.0f);
    }
    unsafeAtomicAdd(&h[(size_t)cur * H + lane], acc);
}

// ------- GraphNorm + relu, in place; refresh h16; optional pool accum -------
__global__ __launch_bounds__(1024) void graphnorm_kernel(
    float* __restrict__ h, u16* __restrict__ h16,
    const int* __restrict__ start,
    const float* __restrict__ w, const float* __restrict__ b,
    const float* __restrict__ a,
    float* __restrict__ pool, int do_pool)
{
    __shared__ float red1[16][H], red2[16][H];
    __shared__ float amean_s[H], rstd_s[H];
    const int g = blockIdx.x;
    const int lane = threadIdx.x & 63;
    const int wv = threadIdx.x >> 6;
    const int s = start[g], e = start[g + 1];

    float s1 = 0.f, s2 = 0.f;
    for (int i = s + wv; i < e; i += 16) {
        float v = h[(size_t)i * H + lane];
        s1 += v; s2 += v * v;
    }
    red1[wv][lane] = s1; red2[wv][lane] = s2;
    __syncthreads();
    if (threadIdx.x < H) {
        float t1 = 0.f, t2 = 0.f;
#pragma unroll
        for (int k = 0; k < 16; ++k) { t1 += red1[k][lane]; t2 += red2[k][lane]; }
        float cnt = fmaxf((float)(e - s), 1.0f);
        float mean = t1 / cnt;
        float alpha = a[lane];
        float var = t2 / cnt - (2.0f * alpha - alpha * alpha) * mean * mean;
        var = fmaxf(var, 0.0f);
        amean_s[lane] = alpha * mean;
        rstd_s[lane] = rsqrtf(var + EPSV);
    }
    __syncthreads();
    const float am = amean_s[lane], rstd = rstd_s[lane];
    const float ww = w[lane], bb = b[lane];
    float ps = 0.f;
    for (int i = s + wv; i < e; i += 16) {
        float v = (h[(size_t)i * H + lane] - am) * rstd * ww + bb;
        v = fmaxf(v, 0.0f);
        h[(size_t)i * H + lane] = v;
        h16[(size_t)i * H + lane] = f2bf(v);
        ps += v;
    }
    if (do_pool && e > s) unsafeAtomicAdd(&pool[g * H + lane], ps);
}

// ---------------- readout from pooled sums ----------------------------------
__global__ __launch_bounds__(64) void final_kernel(
    const float* __restrict__ pool,
    const float* __restrict__ W1, const float* __restrict__ b1,
    const float* __restrict__ W2, const float* __restrict__ b2,
    float* __restrict__ out)
{
    const int g = blockIdx.x;
    const int lane = threadIdx.x;
    const float gv = pool[g * H + lane];
    float acc = b1[lane];
#pragma unroll
    for (int d = 0; d < H; ++d)
        acc = fmaf(__shfl(gv, d, 64), W1[d * H + lane], acc);
    float r = fmaxf(acc, 0.0f);
    float v = r * W2[lane];
#pragma unroll
    for (int o = 32; o > 0; o >>= 1) v += __shfl_xor(v, o, 64);
    if (lane == 0) out[g] = v + b2[0];
}

extern "C" void kernel_launch(void* const* d_in, const int* in_sizes, int n_in,
                              void* d_out, int out_size, void* d_ws, size_t ws_size,
                              hipStream_t stream)
{
    const float* x      = (const float*)d_in[0];
    const int*   ei     = (const int*)  d_in[1];
    const float* ea     = (const float*)d_in[2];
    const int*   batch  = (const int*)  d_in[3];
    const float* ligW1  = (const float*)d_in[4];
    const float* ligb1  = (const float*)d_in[5];
    const float* ligW2  = (const float*)d_in[6];
    const float* ligb2  = (const float*)d_in[7];
    const float* protW1 = (const float*)d_in[8];
    const float* protb1 = (const float*)d_in[9];
    const float* protW2 = (const float*)d_in[10];
    const float* protb2 = (const float*)d_in[11];
    const float* convWe = (const float*)d_in[12];
    const float* convbe = (const float*)d_in[13];
    const float* convW1 = (const float*)d_in[14];
    const float* convb1 = (const float*)d_in[15];
    const float* convW2 = (const float*)d_in[16];
    const float* convb2 = (const float*)d_in[17];
    const float* normw  = (const float*)d_in[18];
    const float* normb  = (const float*)d_in[19];
    const float* norma  = (const float*)d_in[20];
    const float* outW1  = (const float*)d_in[21];
    const float* outb1  = (const float*)d_in[22];
    const float* outW2  = (const float*)d_in[23];
    const float* outb2  = (const float*)d_in[24];

    float* out = (float*)d_out;

    // -------- workspace layout (16B-aligned blocks first) -------------------
    float* h         = (float*)d_ws;                    // NN*H f32      25.6 MB
    uint4* eab       = (uint4*)(h + (size_t)NN * H);    // NE uint4      25.6 MB
    int2*  perm2     = (int2*)(eab + (size_t)NE);       // NE int2       12.8 MB
    u16*   h16       = (u16*)(perm2 + (size_t)NE);      // NN*H u16      12.8 MB
    u16*   xb        = h16 + (size_t)NN * H;            // NN*H u16      12.8 MB
    u16*   wf        = xb + (size_t)NN * H;             // 40960 u16     80 KB
    int4*  tmp_sde   = (int4*)h;                        // NE int4 (overlay h, 25.6 MB)

    int*   ctr       = (int*)(wf + 40960);              // 2     (zeroed)
    int*   gbcount   = ctr + 2;                         // NBK   (zeroed)
    float* pool      = (float*)(gbcount + NBK);         // GNUM*H (zeroed)
    int*   gstart    = (int*)(pool + GNUM * H);         // NBK+1
    int*   gcur      = gstart + (NBK + 1);              // NBK
    int*   start     = gcur + NBK;                      // GNUM+1
    int*   lig_list  = start + (GNUM + 1);              // NN
    int*   prot_list = lig_list + NN;                   // NN

    hipMemsetAsync(ctr, 0, ((size_t)2 + NBK + GNUM * H) * sizeof(int), stream);

    // ---- independent prep (doesn't touch overlays) ----
    xb_kernel<<<(NN * H + 255) / 256, 256, 0, stream>>>(x, xb);
    prep_w_kernel<<<(10 * 4096 + 255) / 256, 256, 0, stream>>>(
        ligW1, ligW2, protW1, protW2, convW1, convW2, wf);
    partition_kernel<<<(NN + 255) / 256, 256, 0, stream>>>(x, ctr, lig_list, prot_list);
    bounds_kernel<<<2, 256, 0, stream>>>(batch, start);

    // ---- CSR build: bucket hist -> scan -> partition -> per-bucket sort ----
    bhist_kernel<<<NBLK_E, 256, 0, stream>>>(ei, gbcount);
    bscan_kernel<<<1, 256, 0, stream>>>(gbcount, gstart, gcur);
    p1_kernel<<<NBLK_P1, 1024, 0, stream>>>(ei, gcur, tmp_sde);
    sort_kernel<<<NBK, 1024, 0, stream>>>(tmp_sde, ea, gstart, perm2, eab);

    // ---- encoder (MFMA over lig/prot lists; after overlays are dead) ----
    const int enc_blocks = (NTILE + 3) / 4;
    enc_mfma_kernel<<<enc_blocks, 256, 0, stream>>>(
        lig_list, &ctr[0], xb, wf + 0 * 4096, wf + 1 * 4096, ligb1, ligb2, h, h16);
    enc_mfma_kernel<<<enc_blocks, 256, 0, stream>>>(
        prot_list, &ctr[1], xb, wf + 2 * 4096, wf + 3 * 4096, protb1, protb2, h, h16);

    const int aggr_blocks = NE / EPW / 4;   // 25000, exact
    const int mlp_blocks = (NTILE + 3) / 4;
    for (int l = 0; l < 3; ++l) {
        aggr_kernel<<<aggr_blocks, 256, 0, stream>>>(
            perm2, (const u32*)eab,
            convWe + (size_t)l * EDIM * H, convbe + (size_t)l * H, h16, h);
        mlp_mfma_kernel<<<mlp_blocks, 256, 0, stream>>>(
            wf + (size_t)(4 + 2 * l) * 4096, wf + (size_t)(5 + 2 * l) * 4096,
            convb1 + (size_t)l * H, convb2 + (size_t)l * H, h);
        graphnorm_kernel<<<GNUM, 1024, 0, stream>>>(
            h, h16, start, normw + (size_t)l * H, normb + (size_t)l * H,
            norma + (size_t)l * H, pool, (l == 2) ? 1 : 0);
    }
    final_kernel<<<GNUM, 64, 0, stream>>>(pool, outW1, outb1, outW2, outb2, out);
}

// Round 12
// 603.730 us; speedup vs baseline: 1.5675x; 1.0181x over previous
//
#include <hip/hip_runtime.h>

#define NN 100000   // nodes
#define NE 1600000  // edges
#define IN_CH 41
#define EDIM 8
#define H 64
#define GNUM 256
#define ATOM 21
#define EPSV 1e-5f
#define EPW 16      // edges per wave in aggr (NE % EPW == 0)
#define NTILE (NN / 16)   // 6250 node tiles (exact)

#define BSH 9       // bucket shift: dst>>9, 512 dst per bucket
#define NBK 196     // ceil(NN / 512)
#define QD 128      // dst per quarter-pass in sort
#define SCAP 2560   // LDS stage capacity per quarter (mean ~2041, +11 sigma)
#define VPT 8       // edges per thread in bucket kernels
#define EPB (256 * VPT)                    // 2048 edges per block (bhist)
#define NBLK_E ((NE + EPB - 1) / EPB)      // 782
#define EPB_P1 (1024 * VPT)                // 8192 edges per block (p1)
#define NBLK_P1 ((NE + EPB_P1 - 1) / EPB_P1)  // 196

typedef unsigned short u16;
typedef unsigned int u32;
typedef unsigned long long u64;
typedef __attribute__((ext_vector_type(8))) short short8;
typedef __attribute__((ext_vector_type(4))) float floatx4;

__device__ __forceinline__ u16 f2bf(float f) {
    u32 u = __float_as_uint(f);
    u32 r = (u + 0x7FFFu + ((u >> 16) & 1u)) >> 16;   // RNE
    return (u16)r;
}
__device__ __forceinline__ float bf2f(u16 u) {
    return __uint_as_float(((u32)u) << 16);
}
__device__ __forceinline__ floatx4 mfma16(short8 a, short8 b, floatx4 c) {
    return __builtin_amdgcn_mfma_f32_16x16x32_bf16(a, b, c, 0, 0, 0);
}
__device__ __forceinline__ short8 pack_bf8(float4 a, float4 b) {
    short8 s;
    s[0] = (short)f2bf(a.x); s[1] = (short)f2bf(a.y);
    s[2] = (short)f2bf(a.z); s[3] = (short)f2bf(a.w);
    s[4] = (short)f2bf(b.x); s[5] = (short)f2bf(b.y);
    s[6] = (short)f2bf(b.z); s[7] = (short)f2bf(b.w);
    return s;
}

// ---- partition: mask per node -> lig_list / prot_list ----------------------
__global__ __launch_bounds__(256) void partition_kernel(
    const float* __restrict__ x, int* __restrict__ ctr,
    int* __restrict__ lig_list, int* __restrict__ prot_list)
{
    const int n = blockIdx.x * 256 + threadIdx.x;
    const int lane = threadIdx.x & 63;
    float m = 0.0f;
    if (n < NN) {
        const float* xr = x + (size_t)n * IN_CH + ATOM;
#pragma unroll
        for (int d = 0; d < IN_CH - ATOM; ++d) m += fabsf(xr[d]);
    }
    const bool valid = n < NN;
    const bool prot = valid && (m > 1e-6f);
    const bool lig = valid && !prot;

    const u64 bl = __ballot(lig);
    const u64 bp = __ballot(prot);
    const u64 below_m = (lane == 63) ? (~0ull >> 1) : ((1ull << lane) - 1ull);
    int base_l = 0, base_p = 0;
    if (lane == 0) {
        if (bl) base_l = atomicAdd(&ctr[0], (int)__popcll(bl));
        if (bp) base_p = atomicAdd(&ctr[1], (int)__popcll(bp));
    }
    base_l = __shfl(base_l, 0, 64);
    base_p = __shfl(base_p, 0, 64);
    if (lig)  lig_list [base_l + (int)__popcll(bl & below_m)] = n;
    if (prot) prot_list[base_p + (int)__popcll(bp & below_m)] = n;
}

// ---- xb: zero-padded bf16 copy of x [NN x 64] ------------------------------
__global__ __launch_bounds__(256) void xb_kernel(
    const float* __restrict__ x, u16* __restrict__ xb)
{
    const int id = blockIdx.x * 256 + threadIdx.x;
    if (id >= NN * H) return;
    const int n = id >> 6, d = id & 63;
    xb[id] = (d < IN_CH) ? f2bf(x[(size_t)n * IN_CH + d]) : (u16)0;
}

// ---- ea -> bf16x8 in original edge order (fully coalesced) -----------------
__global__ __launch_bounds__(256) void ea2b_kernel(
    const float* __restrict__ ea, uint4* __restrict__ eab16g)
{
    const int e = blockIdx.x * 256 + threadIdx.x;
    if (e >= NE) return;
    const float4* e4 = (const float4*)(ea + (size_t)e * EDIM);
    const float4 a = e4[0], b = e4[1];
    uint4 u;
    u.x = (u32)f2bf(a.x) | ((u32)f2bf(a.y) << 16);
    u.y = (u32)f2bf(a.z) | ((u32)f2bf(a.w) << 16);
    u.z = (u32)f2bf(b.x) | ((u32)f2bf(b.y) << 16);
    u.w = (u32)f2bf(b.z) | ((u32)f2bf(b.w) << 16);
    eab16g[e] = u;
}

// ---- prep: swizzle 10 weight matrices into MFMA B-fragment order -----------
__global__ __launch_bounds__(256) void prep_w_kernel(
    const float* __restrict__ ligW1, const float* __restrict__ ligW2,
    const float* __restrict__ protW1, const float* __restrict__ protW2,
    const float* __restrict__ convW1, const float* __restrict__ convW2,
    u16* __restrict__ wf)
{
    const int id = blockIdx.x * 256 + threadIdx.x;
    if (id >= 10 * 4096) return;
    const int j = id & 7, l = (id >> 3) & 63, t = (id >> 9) & 3;
    const int c = (id >> 11) & 1, mat = id >> 12;
    const int k = c * 32 + ((l >> 4) * 8) + j;
    const int n = t * 16 + (l & 15);
    const float* src; int K = 64;
    if (mat == 0)      { src = ligW1;  K = IN_CH; }
    else if (mat == 1) { src = ligW2; }
    else if (mat == 2) { src = protW1; K = IN_CH; }
    else if (mat == 3) { src = protW2; }
    else {
        const int layer = (mat - 4) >> 1;
        src = (((mat - 4) & 1) ? convW2 : convW1) + (size_t)layer * H * H;
    }
    wf[id] = (k < K) ? f2bf(src[(size_t)k * H + n]) : (u16)0;
}

// ---- MFMA MLP over a gathered node list (encoder) --------------------------
__global__ __launch_bounds__(256) void enc_mfma_kernel(
    const int* __restrict__ list, const int* __restrict__ countPtr,
    const u16* __restrict__ xb,
    const u16* __restrict__ w1f, const u16* __restrict__ w2f,
    const float* __restrict__ bia1, const float* __restrict__ bia2,
    float* __restrict__ h, u16* __restrict__ h16)
{
    __shared__ __align__(16) u16 hid[4][16 * 72];
    const int wv = threadIdx.x >> 6;
    const int lane = threadIdx.x & 63;
    const int tile = blockIdx.x * 4 + wv;
    const int count = *countPtr;
    if (tile * 16 >= count) return;
    const int quad = lane >> 4;
    const int mi = lane & 15;
    int idx = tile * 16 + mi;
    if (idx >= count) idx = count - 1;
    const int nid = list[idx];

    const short8 a0 = *(const short8*)(xb + (size_t)nid * H + quad * 8);
    const short8 a1 = *(const short8*)(xb + (size_t)nid * H + 32 + quad * 8);

    floatx4 acc[4];
#pragma unroll
    for (int t = 0; t < 4; ++t) acc[t] = (floatx4){0.f, 0.f, 0.f, 0.f};
#pragma unroll
    for (int t = 0; t < 4; ++t) {
        const short8 b0 = *(const short8*)(w1f + ((size_t)(0 * 4 + t) * 64 + lane) * 8);
        const short8 b1 = *(const short8*)(w1f + ((size_t)(1 * 4 + t) * 64 + lane) * 8);
        acc[t] = mfma16(a0, b0, acc[t]);
        acc[t] = mfma16(a1, b1, acc[t]);
    }

    u16* myh = hid[wv];
#pragma unroll
    for (int t = 0; t < 4; ++t) {
        const float bv = bia1[t * 16 + mi];
#pragma unroll
        for (int r = 0; r < 4; ++r) {
            const float v = fmaxf(acc[t][r] + bv, 0.0f);
            myh[(quad * 4 + r) * 72 + t * 16 + mi] = f2bf(v);
        }
    }
    asm volatile("s_waitcnt lgkmcnt(0)" ::: "memory");

    const short8 c0 = *(const short8*)(myh + mi * 72 + quad * 8);
    const short8 c1 = *(const short8*)(myh + mi * 72 + 32 + quad * 8);

    floatx4 acc2[4];
#pragma unroll
    for (int t = 0; t < 4; ++t) acc2[t] = (floatx4){0.f, 0.f, 0.f, 0.f};
#pragma unroll
    for (int t = 0; t < 4; ++t) {
        const short8 b0 = *(const short8*)(w2f + ((size_t)(0 * 4 + t) * 64 + lane) * 8);
        const short8 b1 = *(const short8*)(w2f + ((size_t)(1 * 4 + t) * 64 + lane) * 8);
        acc2[t] = mfma16(c0, b0, acc2[t]);
        acc2[t] = mfma16(c1, b1, acc2[t]);
    }

#pragma unroll
    for (int t = 0; t < 4; ++t) {
        const float bv = bia2[t * 16 + mi];
#pragma unroll
        for (int r = 0; r < 4; ++r) {
            const int row = quad * 4 + r;
            const int nr = __shfl(nid, row, 64);
            if (tile * 16 + row < count) {
                const float v = fmaxf(acc2[t][r] + bv, 0.0f);
                h[(size_t)nr * H + t * 16 + mi] = v;
                h16[(size_t)nr * H + t * 16 + mi] = f2bf(v);
            }
        }
    }
}

// ---- MFMA MLP over consecutive nodes, in place (conv nn), no outer relu ----
__global__ __launch_bounds__(256) void mlp_mfma_kernel(
    const u16* __restrict__ w1f, const u16* __restrict__ w2f,
    const float* __restrict__ bia1, const float* __restrict__ bia2,
    float* __restrict__ h)
{
    __shared__ __align__(16) u16 hid[4][16 * 72];
    const int wv = threadIdx.x >> 6;
    const int lane = threadIdx.x & 63;
    const int tile = blockIdx.x * 4 + wv;
    if (tile >= NTILE) return;
    const int quad = lane >> 4;
    const int mi = lane & 15;
    const int row = tile * 16 + mi;
    const float* zr = h + (size_t)row * H;

    const float4 f0 = *(const float4*)(zr + quad * 8);
    const float4 f1 = *(const float4*)(zr + quad * 8 + 4);
    const float4 f2 = *(const float4*)(zr + 32 + quad * 8);
    const float4 f3 = *(const float4*)(zr + 32 + quad * 8 + 4);
    const short8 a0 = pack_bf8(f0, f1);
    const short8 a1 = pack_bf8(f2, f3);

    floatx4 acc[4];
#pragma unroll
    for (int t = 0; t < 4; ++t) acc[t] = (floatx4){0.f, 0.f, 0.f, 0.f};
#pragma unroll
    for (int t = 0; t < 4; ++t) {
        const short8 b0 = *(const short8*)(w1f + ((size_t)(0 * 4 + t) * 64 + lane) * 8);
        const short8 b1 = *(const short8*)(w1f + ((size_t)(1 * 4 + t) * 64 + lane) * 8);
        acc[t] = mfma16(a0, b0, acc[t]);
        acc[t] = mfma16(a1, b1, acc[t]);
    }

    u16* myh = hid[wv];
#pragma unroll
    for (int t = 0; t < 4; ++t) {
        const float bv = bia1[t * 16 + mi];
#pragma unroll
        for (int r = 0; r < 4; ++r) {
            const float v = fmaxf(acc[t][r] + bv, 0.0f);
            myh[(quad * 4 + r) * 72 + t * 16 + mi] = f2bf(v);
        }
    }
    asm volatile("s_waitcnt lgkmcnt(0)" ::: "memory");

    const short8 c0 = *(const short8*)(myh + mi * 72 + quad * 8);
    const short8 c1 = *(const short8*)(myh + mi * 72 + 32 + quad * 8);

    floatx4 acc2[4];
#pragma unroll
    for (int t = 0; t < 4; ++t) acc2[t] = (floatx4){0.f, 0.f, 0.f, 0.f};
#pragma unroll
    for (int t = 0; t < 4; ++t) {
        const short8 b0 = *(const short8*)(w2f + ((size_t)(0 * 4 + t) * 64 + lane) * 8);
        const short8 b1 = *(const short8*)(w2f + ((size_t)(1 * 4 + t) * 64 + lane) * 8);
        acc2[t] = mfma16(c0, b0, acc2[t]);
        acc2[t] = mfma16(c1, b1, acc2[t]);
    }

#pragma unroll
    for (int t = 0; t < 4; ++t) {
        const float bv = bia2[t * 16 + mi];
#pragma unroll
        for (int r = 0; r < 4; ++r) {
            const int orow = tile * 16 + quad * 4 + r;
            h[(size_t)orow * H + t * 16 + mi] = acc2[t][r] + bv;
        }
    }
}

// ---------------- per-graph node ranges (batch is sorted) -------------------
__global__ void bounds_kernel(const int* __restrict__ batch, int* __restrict__ start)
{
    int g = blockIdx.x * blockDim.x + threadIdx.x;
    if (g > GNUM) return;
    int lo = 0, hi = NN;
    while (lo < hi) {
        int mid = (lo + hi) >> 1;
        if (batch[mid] < g) lo = mid + 1; else hi = mid;
    }
    start[g] = lo;
}

// ---- bucket histogram (LDS only) -------------------------------------------
__global__ __launch_bounds__(256) void bhist_kernel(
    const int* __restrict__ ei, int* __restrict__ gbcount)
{
    __shared__ int cnt[NBK];
    const int t = threadIdx.x;
    if (t < NBK) cnt[t] = 0;
    __syncthreads();
    const int base = blockIdx.x * EPB;
#pragma unroll
    for (int v = 0; v < VPT; ++v) {
        const int e = base + v * 256 + t;
        if (e < NE) atomicAdd(&cnt[ei[NE + e] >> BSH], 1);
    }
    __syncthreads();
    if (t < NBK && cnt[t]) atomicAdd(&gbcount[t], cnt[t]);
}

// ---- exclusive scan of bucket counts -> gstart (and gcur working copy) -----
__global__ __launch_bounds__(256) void bscan_kernel(
    const int* __restrict__ gbcount, int* __restrict__ gstart, int* __restrict__ gcur)
{
    __shared__ int s[256];
    const int t = threadIdx.x;
    int v = (t < NBK) ? gbcount[t] : 0;
    s[t] = v;
    __syncthreads();
#pragma unroll
    for (int off = 1; off < 256; off <<= 1) {
        int tmp = (t >= off) ? s[t - off] : 0;
        __syncthreads();
        s[t] += tmp;
        __syncthreads();
    }
    if (t < NBK) { gstart[t] = s[t] - v; gcur[t] = s[t] - v; }
    if (t == 0) gstart[NBK] = NE;
}

// ---- phase 1: bucket partition of (src,dst,eid) records, 16B stores --------
__global__ __launch_bounds__(1024) void p1_kernel(
    const int* __restrict__ ei,
    int* __restrict__ gcur,
    int4* __restrict__ tmp_sde)
{
    __shared__ int cnt[NBK];
    __shared__ int cur[NBK];
    const int t = threadIdx.x;
    if (t < NBK) cnt[t] = 0;
    __syncthreads();
    const int base = blockIdx.x * EPB_P1;
    int dstv[VPT];
#pragma unroll
    for (int v = 0; v < VPT; ++v) {
        const int e = base + v * 1024 + t;
        dstv[v] = -1;
        if (e < NE) {
            dstv[v] = ei[NE + e];
            atomicAdd(&cnt[dstv[v] >> BSH], 1);
        }
    }
    __syncthreads();
    if (t < NBK) cur[t] = cnt[t] ? atomicAdd(&gcur[t], cnt[t]) : 0;
    __syncthreads();
#pragma unroll
    for (int v = 0; v < VPT; ++v) {
        const int e = base + v * 1024 + t;
        if (e < NE) {
            const int b = dstv[v] >> BSH;
            const int pos = atomicAdd(&cur[b], 1);
            tmp_sde[pos] = make_int4(ei[e], dstv[v], e, 0);
        }
    }
}

// ---- per-bucket counting sort, LDS-staged, 4 quarter-passes ----------------
// Writes perm2/eab fully coalesced; gathers pre-converted bf16 edge feats.
__global__ __launch_bounds__(1024) void sort_kernel(
    const int4* __restrict__ tmp_sde, const uint4* __restrict__ eab16g,
    const int* __restrict__ gstart,
    int2* __restrict__ perm2, uint4* __restrict__ eab)
{
    __shared__ int hist[QD];
    __shared__ int cursor[QD];
    __shared__ int qcnt_s;
    __shared__ __align__(16) int4 stage[SCAP];
    const int b = blockIdx.x;
    const int t = threadIdx.x;
    const int s = gstart[b], e = gstart[b + 1];
    const int dbase = b << BSH;

    int qprev = 0;   // edges emitted in previous quarters
    for (int q = 0; q < 4; ++q) {
        const int qlo = dbase + q * QD;
        if (t < QD) hist[t] = 0;
        __syncthreads();
        for (int i = s + t; i < e; i += 1024) {
            const u32 rd = (u32)(tmp_sde[i].y - qlo);
            if (rd < QD) atomicAdd(&hist[rd], 1);
        }
        __syncthreads();
        if (t < QD) cursor[t] = hist[t];
        __syncthreads();
#pragma unroll
        for (int off = 1; off < QD; off <<= 1) {
            int v = (t < QD && t >= off) ? cursor[t - off] : 0;
            __syncthreads();
            if (t < QD) cursor[t] += v;   // inclusive
            __syncthreads();
        }
        if (t == QD - 1) qcnt_s = cursor[QD - 1];
        if (t < QD) cursor[t] -= hist[t];  // exclusive
        __syncthreads();
        const int qcnt = qcnt_s;
        const int base = s + qprev;

        if (qcnt <= SCAP) {
            // scatter into LDS stage (cheap), then flush coalesced
            for (int i = s + t; i < e; i += 1024) {
                const int4 rec = tmp_sde[i];
                const u32 rd = (u32)(rec.y - qlo);
                if (rd < QD) {
                    const int slot = atomicAdd(&cursor[rd], 1);
                    stage[slot] = rec;
                }
            }
            __syncthreads();
            for (int i = t; i < qcnt; i += 1024) {
                const int4 rec = stage[i];
                perm2[base + i] = make_int2(rec.x, rec.y);
                eab[base + i] = eab16g[rec.z];
            }
        } else {
            // fallback: direct global scatter (should never happen)
            if (t < QD) cursor[t] += base;
            __syncthreads();
            for (int i = s + t; i < e; i += 1024) {
                const int4 rec = tmp_sde[i];
                const u32 rd = (u32)(rec.y - qlo);
                if (rd < QD) {
                    const int pos = atomicAdd(&cursor[rd], 1);
                    perm2[pos] = make_int2(rec.x, rec.y);
                    eab[pos] = eab16g[rec.z];
                }
            }
        }
        qprev += qcnt;
        __syncthreads();
    }
}

// ---- edge-centric aggregation: one wave per 16 consecutive CSR edges -------
__global__ __launch_bounds__(256) void aggr_kernel(
    const int2* __restrict__ perm2,
    const u32* __restrict__ eab32,
    const float* __restrict__ We, const float* __restrict__ be,
    const u16* __restrict__ h16, float* __restrict__ h)
{
    const int lane = threadIdx.x & 63;
    const int chunk = blockIdx.x * 4 + (threadIdx.x >> 6);
    const int base = chunk * EPW;

    float we_r[EDIM];
#pragma unroll
    for (int d = 0; d < EDIM; ++d) we_r[d] = We[d * H + lane];
    const float be_r = be[lane];

    const int2 pd = perm2[base + (lane & 15)];
    const u32 eu = eab32[(size_t)base * 4 + lane];

    float hv[EPW];
#pragma unroll
    for (int j = 0; j < EPW; ++j) {
        const int sj = __builtin_amdgcn_readlane(pd.x, j);
        hv[j] = bf2f(h16[(size_t)sj * H + lane]);
    }

    float acc = 0.0f;
    int cur = __builtin_amdgcn_readlane(pd.y, 0);
#pragma unroll
    for (int j = 0; j < EPW; ++j) {
        const int dj = __builtin_amdgcn_readlane(pd.y, j);
        float msg = be_r;
#pragma unroll
        for (int p = 0; p < 4; ++p) {
            const u32 w2 = __builtin_amdgcn_readlane(eu, j * 4 + p);
            msg = fmaf(__uint_as_float(w2 << 16), we_r[2 * p], msg);
            msg = fmaf(__uint_as_float(w2 & 0xffff0000u), we_r[2 * p + 1], msg);
        }
        if (dj != cur) {                       // wave-uniform branch
            unsafeAtomicAdd(&h[(size_t)cur * H + lane], acc);
            acc = 0.0f;
            cur = dj;
        }
        acc += fmaxf(hv[j] + msg, 0.0f);
    }
    unsafeAtomicAdd(&h[(size_t)cur * H + lane], acc);
}

// ------- GraphNorm + relu, in place; refresh h16; optional pool accum -------
__global__ __launch_bounds__(1024) void graphnorm_kernel(
    float* __restrict__ h, u16* __restrict__ h16,
    const int* __restrict__ start,
    const float* __restrict__ w, const float* __restrict__ b,
    const float* __restrict__ a,
    float* __restrict__ pool, int do_pool)
{
    __shared__ float red1[16][H], red2[16][H];
    __shared__ float amean_s[H], rstd_s[H];
    const int g = blockIdx.x;
    const int lane = threadIdx.x & 63;
    const int wv = threadIdx.x >> 6;
    const int s = start[g], e = start[g + 1];

    float s1 = 0.f, s2 = 0.f;
    for (int i = s + wv; i < e; i += 16) {
        float v = h[(size_t)i * H + lane];
        s1 += v; s2 += v * v;
    }
    red1[wv][lane] = s1; red2[wv][lane] = s2;
    __syncthreads();
    if (threadIdx.x < H) {
        float t1 = 0.f, t2 = 0.f;
#pragma unroll
        for (int k = 0; k < 16; ++k) { t1 += red1[k][lane]; t2 += red2[k][lane]; }
        float cnt = fmaxf((float)(e - s), 1.0f);
        float mean = t1 / cnt;
        float alpha = a[lane];
        float var = t2 / cnt - (2.0f * alpha - alpha * alpha) * mean * mean;
        var = fmaxf(var, 0.0f);
        amean_s[lane] = alpha * mean;
        rstd_s[lane] = rsqrtf(var + EPSV);
    }
    __syncthreads();
    const float am = amean_s[lane], rstd = rstd_s[lane];
    const float ww = w[lane], bb = b[lane];
    float ps = 0.f;
    for (int i = s + wv; i < e; i += 16) {
        float v = (h[(size_t)i * H + lane] - am) * rstd * ww + bb;
        v = fmaxf(v, 0.0f);
        h[(size_t)i * H + lane] = v;
        h16[(size_t)i * H + lane] = f2bf(v);
        ps += v;
    }
    if (do_pool && e > s) unsafeAtomicAdd(&pool[g * H + lane], ps);
}

// ---------------- readout from pooled sums ----------------------------------
__global__ __launch_bounds__(64) void final_kernel(
    const float* __restrict__ pool,
    const float* __restrict__ W1, const float* __restrict__ b1,
    const float* __restrict__ W2, const float* __restrict__ b2,
    float* __restrict__ out)
{
    const int g = blockIdx.x;
    const int lane = threadIdx.x;
    const float gv = pool[g * H + lane];
    float acc = b1[lane];
#pragma unroll
    for (int d = 0; d < H; ++d)
        acc = fmaf(__shfl(gv, d, 64), W1[d * H + lane], acc);
    float r = fmaxf(acc, 0.0f);
    float v = r * W2[lane];
#pragma unroll
    for (int o = 32; o > 0; o >>= 1) v += __shfl_xor(v, o, 64);
    if (lane == 0) out[g] = v + b2[0];
}

extern "C" void kernel_launch(void* const* d_in, const int* in_sizes, int n_in,
                              void* d_out, int out_size, void* d_ws, size_t ws_size,
                              hipStream_t stream)
{
    const float* x      = (const float*)d_in[0];
    const int*   ei     = (const int*)  d_in[1];
    const float* ea     = (const float*)d_in[2];
    const int*   batch  = (const int*)  d_in[3];
    const float* ligW1  = (const float*)d_in[4];
    const float* ligb1  = (const float*)d_in[5];
    const float* ligW2  = (const float*)d_in[6];
    const float* ligb2  = (const float*)d_in[7];
    const float* protW1 = (const float*)d_in[8];
    const float* protb1 = (const float*)d_in[9];
    const float* protW2 = (const float*)d_in[10];
    const float* protb2 = (const float*)d_in[11];
    const float* convWe = (const float*)d_in[12];
    const float* convbe = (const float*)d_in[13];
    const float* convW1 = (const float*)d_in[14];
    const float* convb1 = (const float*)d_in[15];
    const float* convW2 = (const float*)d_in[16];
    const float* convb2 = (const float*)d_in[17];
    const float* normw  = (const float*)d_in[18];
    const float* normb  = (const float*)d_in[19];
    const float* norma  = (const float*)d_in[20];
    const float* outW1  = (const float*)d_in[21];
    const float* outb1  = (const float*)d_in[22];
    const float* outW2  = (const float*)d_in[23];
    const float* outb2  = (const float*)d_in[24];

    float* out = (float*)d_out;

    // -------- workspace layout (16B-aligned blocks first) -------------------
    float* h         = (float*)d_ws;                    // NN*H f32      25.6 MB
    uint4* eab       = (uint4*)(h + (size_t)NN * H);    // NE uint4      25.6 MB
    int2*  perm2     = (int2*)(eab + (size_t)NE);       // NE int2       12.8 MB
    u16*   h16       = (u16*)(perm2 + (size_t)NE);      // NN*H u16      12.8 MB
    u16*   xb        = h16 + (size_t)NN * H;            // NN*H u16      12.8 MB
    u16*   wf        = xb + (size_t)NN * H;             // 40960 u16     80 KB
    int4*  tmp_sde   = (int4*)h;                        // NE int4 (overlay h)
    uint4* eab16g    = (uint4*)h16;                     // NE uint4 (overlay h16+xb)

    int*   ctr       = (int*)(wf + 40960);              // 2     (zeroed)
    int*   gbcount   = ctr + 2;                         // NBK   (zeroed)
    float* pool      = (float*)(gbcount + NBK);         // GNUM*H (zeroed)
    int*   gstart    = (int*)(pool + GNUM * H);         // NBK+1
    int*   gcur      = gstart + (NBK + 1);              // NBK
    int*   start     = gcur + NBK;                      // GNUM+1
    int*   lig_list  = start + (GNUM + 1);              // NN
    int*   prot_list = lig_list + NN;                   // NN

    hipMemsetAsync(ctr, 0, ((size_t)2 + NBK + GNUM * H) * sizeof(int), stream);

    // ---- prep not touching overlays ----
    prep_w_kernel<<<(10 * 4096 + 255) / 256, 256, 0, stream>>>(
        ligW1, ligW2, protW1, protW2, convW1, convW2, wf);
    partition_kernel<<<(NN + 255) / 256, 256, 0, stream>>>(x, ctr, lig_list, prot_list);
    bounds_kernel<<<2, 256, 0, stream>>>(batch, start);

    // ---- CSR build: hist -> scan -> ea conv -> partition -> staged sort ----
    bhist_kernel<<<NBLK_E, 256, 0, stream>>>(ei, gbcount);
    bscan_kernel<<<1, 256, 0, stream>>>(gbcount, gstart, gcur);
    ea2b_kernel<<<(NE + 255) / 256, 256, 0, stream>>>(ea, eab16g);
    p1_kernel<<<NBLK_P1, 1024, 0, stream>>>(ei, gcur, tmp_sde);
    sort_kernel<<<NBK, 1024, 0, stream>>>(tmp_sde, eab16g, gstart, perm2, eab);

    // ---- xb after eab16g overlay is dead; then encoder ----
    xb_kernel<<<(NN * H + 255) / 256, 256, 0, stream>>>(x, xb);
    const int enc_blocks = (NTILE + 3) / 4;
    enc_mfma_kernel<<<enc_blocks, 256, 0, stream>>>(
        lig_list, &ctr[0], xb, wf + 0 * 4096, wf + 1 * 4096, ligb1, ligb2, h, h16);
    enc_mfma_kernel<<<enc_blocks, 256, 0, stream>>>(
        prot_list, &ctr[1], xb, wf + 2 * 4096, wf + 3 * 4096, protb1, protb2, h, h16);

    const int aggr_blocks = NE / EPW / 4;   // 25000, exact
    const int mlp_blocks = (NTILE + 3) / 4;
    for (int l = 0; l < 3; ++l) {
        aggr_kernel<<<aggr_blocks, 256, 0, stream>>>(
            perm2, (const u32*)eab,
            convWe + (size_t)l * EDIM * H, convbe + (size_t)l * H, h16, h);
        mlp_mfma_kernel<<<mlp_blocks, 256, 0, stream>>>(
            wf + (size_t)(4 + 2 * l) * 4096, wf + (size_t)(5 + 2 * l) * 4096,
            convb1 + (size_t)l * H, convb2 + (size_t)l * H, h);
        graphnorm_kernel<<<GNUM, 1024, 0, stream>>>(
            h, h16, start, normw + (size_t)l * H, normb + (size_t)l * H,
            norma + (size_t)l * H, pool, (l == 2) ? 1 : 0);
    }
    final_kernel<<<GNUM, 64, 0, stream>>>(pool, outW1, outb1, outW2, outb2, out);
}